// Round 7
// baseline (857.635 us; speedup 1.0000x reference)
//
#include <hip/hip_runtime.h>
#include <hip/hip_bf16.h>

#define B_    32
#define C_    192
#define N_    784
#define K_    9
#define COUT_ 384
#define NPTS_ (B_ * N_)   // 25088

// ordered-uint transform: monotone map float -> uint
__device__ __forceinline__ unsigned int ford(float f) {
  unsigned int u = __float_as_uint(f);
  return u ^ ((u & 0x80000000u) ? 0xFFFFFFFFu : 0x80000000u);
}

// ---------------------------------------------------------------------------
// K1: fp32 norm (sequential), xn = x/norm (row + transposed), sq = pairwise
// ---------------------------------------------------------------------------
__global__ __launch_bounds__(256) void norm_kernel(
    const float* __restrict__ x, float* __restrict__ xn,
    float* __restrict__ xnT, float* __restrict__ sq) {
  int p = blockIdx.x * 256 + threadIdx.x;
  if (p >= NPTS_) return;
  int b = p / N_, n = p % N_;
  const float* xb = x + (size_t)b * C_ * N_ + n;
  float s = 0.f;
  for (int c = 0; c < C_; c++) {
    float v = xb[(size_t)c * N_];
    s = __fadd_rn(s, __fmul_rn(v, v));
  }
  float nrm = fmaxf(__fsqrt_rn(s), 1e-12f);
  float* xr = xn + (size_t)p * C_;
  float* xt = xnT + (size_t)b * C_ * N_ + n;
  float r0[8], r1[8];
  #pragma unroll
  for (int j = 0; j < 8; j++) {
    float a = __fdiv_rn(xb[(size_t)j * N_], nrm);
    xr[j] = a; xt[(size_t)j * N_] = a;
    r0[j] = __fmul_rn(a, a);
  }
  for (int i = 8; i < 96; i += 8) {
    #pragma unroll
    for (int j = 0; j < 8; j++) {
      float a = __fdiv_rn(xb[(size_t)(i + j) * N_], nrm);
      xr[i + j] = a; xt[(size_t)(i + j) * N_] = a;
      r0[j] = __fadd_rn(r0[j], __fmul_rn(a, a));
    }
  }
  #pragma unroll
  for (int j = 0; j < 8; j++) {
    float a = __fdiv_rn(xb[(size_t)(96 + j) * N_], nrm);
    xr[96 + j] = a; xt[(size_t)(96 + j) * N_] = a;
    r1[j] = __fmul_rn(a, a);
  }
  for (int i = 104; i < 192; i += 8) {
    #pragma unroll
    for (int j = 0; j < 8; j++) {
      float a = __fdiv_rn(xb[(size_t)(i + j) * N_], nrm);
      xr[i + j] = a; xt[(size_t)(i + j) * N_] = a;
      r1[j] = __fadd_rn(r1[j], __fmul_rn(a, a));
    }
  }
  float L = __fadd_rn(
      __fadd_rn(__fadd_rn(r0[0], r0[1]), __fadd_rn(r0[2], r0[3])),
      __fadd_rn(__fadd_rn(r0[4], r0[5]), __fadd_rn(r0[6], r0[7])));
  float R = __fadd_rn(
      __fadd_rn(__fadd_rn(r1[0], r1[1]), __fadd_rn(r1[2], r1[3])),
      __fadd_rn(__fadd_rn(r1[4], r1[5]), __fadd_rn(r1[6], r1[7])));
  sq[p] = __fadd_rn(L, R);
}

// ---------------------------------------------------------------------------
// K2: brute-force KNN, sequential fp32 inner; 9x stable (value,idx) argmin.
// ---------------------------------------------------------------------------
__global__ __launch_bounds__(256) void knn_kernel(
    const float* __restrict__ xn, const float* __restrict__ xnT,
    const float* __restrict__ sq, int* __restrict__ nn9) {
  int p = blockIdx.x;
  int b = p / N_;
  int t = threadIdx.x;

  __shared__ float qv[C_];
  __shared__ float dl[N_];
  __shared__ unsigned long long wmin[4];

  const float* qr = xn + (size_t)p * C_;
  for (int i = t; i < C_; i += 256) qv[i] = qr[i];
  __syncthreads();

  float sqp = sq[p];
  const float* bT  = xnT + (size_t)b * C_ * N_;
  const float* sqb = sq + (size_t)b * N_;
  int m0 = t, m1 = t + 256, m2 = t + 512, m3 = t + 768;
  int m3c = m3 < N_ ? m3 : (N_ - 1);
  float a0 = 0.f, a1 = 0.f, a2 = 0.f, a3 = 0.f;
  for (int c = 0; c < C_; c++) {
    float q = qv[c];
    const float* col = bT + (size_t)c * N_;
    a0 = __fadd_rn(a0, __fmul_rn(q, col[m0]));
    a1 = __fadd_rn(a1, __fmul_rn(q, col[m1]));
    a2 = __fadd_rn(a2, __fmul_rn(q, col[m2]));
    a3 = __fadd_rn(a3, __fmul_rn(q, col[m3c]));
  }
  dl[m0] = __fadd_rn(__fsub_rn(sqp, __fmul_rn(2.0f, a0)), sqb[m0]);
  dl[m1] = __fadd_rn(__fsub_rn(sqp, __fmul_rn(2.0f, a1)), sqb[m1]);
  dl[m2] = __fadd_rn(__fsub_rn(sqp, __fmul_rn(2.0f, a2)), sqb[m2]);
  if (m3 < N_)
    dl[m3] = __fadd_rn(__fsub_rn(sqp, __fmul_rn(2.0f, a3)), sqb[m3]);
  __syncthreads();

  for (int kk = 0; kk < K_; kk++) {
    unsigned long long mk = ~0ull;
    for (int m = t; m < N_; m += 256) {
      unsigned long long key =
          ((unsigned long long)ford(dl[m]) << 10) | (unsigned int)m;
      mk = key < mk ? key : mk;
    }
    #pragma unroll
    for (int off = 1; off < 64; off <<= 1) {
      unsigned long long o = __shfl_xor(mk, off);
      mk = o < mk ? o : mk;
    }
    if ((t & 63) == 0) wmin[t >> 6] = mk;
    __syncthreads();
    unsigned long long fm = wmin[0];
    fm = wmin[1] < fm ? wmin[1] : fm;
    fm = wmin[2] < fm ? wmin[2] : fm;
    fm = wmin[3] < fm ? wmin[3] : fm;
    int widx = (int)(fm & 1023u);
    if (t == 0) {
      nn9[(size_t)p * K_ + kk] = widx;
      dl[widx] = __int_as_float(0x7F800000);  // +inf: drop winner
    }
    __syncthreads();
  }
}

// ---------------------------------------------------------------------------
// K3: gather + max-relative -> h interleaved (B, 2C, N). One block per (c, b).
// ---------------------------------------------------------------------------
__global__ __launch_bounds__(256) void gather_kernel(
    const float* __restrict__ x, const int* __restrict__ nn9,
    float* __restrict__ h) {
  int c = blockIdx.x, b = blockIdx.y;
  int t = threadIdx.x;
  const float* row = x + ((size_t)b * C_ + c) * N_;
  const int* ib = nn9 + (size_t)b * N_ * K_;
  float* h0 = h + ((size_t)b * (2 * C_) + 2 * c) * N_;
  for (int n = t; n < N_; n += 256) {
    float xv = row[n];
    float mx = -1e30f;
    #pragma unroll
    for (int k = 0; k < K_; k++) {
      int idx = ib[n * K_ + k];
      idx = idx < 0 ? 0 : (idx >= N_ ? N_ - 1 : idx);  // defensive clamp
      mx = fmaxf(mx, row[idx]);
    }
    h0[n] = xv;
    h0[N_ + n] = mx - xv;
  }
}

// ---------------------------------------------------------------------------
// K4: grouped 1x1 conv + bias, one block per (co, b); BN partial sums.
// ---------------------------------------------------------------------------
__global__ __launch_bounds__(256) void conv_kernel(
    const float* __restrict__ h, const float* __restrict__ w,
    const float* __restrict__ bias, float* __restrict__ outpre,
    float* __restrict__ psum, float* __restrict__ pss) {
  int co = blockIdx.x, b = blockIdx.y;
  int g = co / 96;
  int t = threadIdx.x;
  __shared__ float wrow[96];
  __shared__ float rs[4], rss[4];
  if (t < 96) wrow[t] = w[(size_t)co * 96 + t];
  __syncthreads();

  float s = 0.f, s2 = 0.f;
  const float* hb = h + ((size_t)b * (2 * C_) + (size_t)g * 96) * N_;
  float bv = bias[co];
  float* orow = outpre + ((size_t)b * COUT_ + co) * N_;
  for (int n4 = t; n4 < N_ / 4; n4 += 256) {
    float4 acc = {bv, bv, bv, bv};
    for (int i = 0; i < 96; i++) {
      float wv = wrow[i];
      float4 hv = *(const float4*)(hb + (size_t)i * N_ + n4 * 4);
      acc.x += wv * hv.x; acc.y += wv * hv.y;
      acc.z += wv * hv.z; acc.w += wv * hv.w;
    }
    *(float4*)(orow + n4 * 4) = acc;
    s += acc.x + acc.y + acc.z + acc.w;
    s2 += acc.x * acc.x + acc.y * acc.y + acc.z * acc.z + acc.w * acc.w;
  }
  #pragma unroll
  for (int off = 1; off < 64; off <<= 1) {
    s += __shfl_xor(s, off);
    s2 += __shfl_xor(s2, off);
  }
  if ((t & 63) == 0) { rs[t >> 6] = s; rss[t >> 6] = s2; }
  __syncthreads();
  if (t == 0) {
    psum[(size_t)co * B_ + b] = rs[0] + rs[1] + rs[2] + rs[3];
    pss [(size_t)co * B_ + b] = rss[0] + rss[1] + rss[2] + rss[3];
  }
}

// ---------------------------------------------------------------------------
// K5: finalize BN stats -> per-channel affine a, b
// ---------------------------------------------------------------------------
__global__ __launch_bounds__(64) void stats_kernel(
    const float* __restrict__ psum, const float* __restrict__ pss,
    const float* __restrict__ gamma, const float* __restrict__ beta,
    float* __restrict__ af, float* __restrict__ bf) {
  int co = blockIdx.x;
  int l = threadIdx.x;
  double s = 0.0, s2 = 0.0;
  for (int i = l; i < B_; i += 64) {
    s  += (double)psum[(size_t)co * B_ + i];
    s2 += (double)pss [(size_t)co * B_ + i];
  }
  #pragma unroll
  for (int o = 32; o > 0; o >>= 1) { s += __shfl_xor(s, o); s2 += __shfl_xor(s2, o); }
  if (l == 0) {
    const double cnt = (double)NPTS_;
    double mean = s / cnt;
    double var  = s2 / cnt - mean * mean;
    double rstd = 1.0 / sqrt(var + 1e-5);
    double a = (double)gamma[co] * rstd;
    af[co] = (float)a;
    bf[co] = (float)((double)beta[co] - mean * a);
  }
}

// ---------------------------------------------------------------------------
// K6: BN affine + exact GELU + fp32 store (output dtype is FLOAT32)
// ---------------------------------------------------------------------------
__global__ __launch_bounds__(256) void act_kernel(
    const float* __restrict__ outpre, const float* __restrict__ af,
    const float* __restrict__ bf, float* __restrict__ out) {
  size_t i = ((size_t)blockIdx.x * 256 + threadIdx.x) * 4;
  int co = (int)((i / N_) % COUT_);     // N_ % 4 == 0 so co uniform in float4
  float a = af[co], c = bf[co];
  float4 v = *(const float4*)(outpre + i);
  float y0 = a * v.x + c, y1 = a * v.y + c, y2 = a * v.z + c, y3 = a * v.w + c;
  const float is2 = 0.70710678118654752f;
  float4 r;
  r.x = 0.5f * y0 * (1.0f + erff(y0 * is2));
  r.y = 0.5f * y1 * (1.0f + erff(y1 * is2));
  r.z = 0.5f * y2 * (1.0f + erff(y2 * is2));
  r.w = 0.5f * y3 * (1.0f + erff(y3 * is2));
  *reinterpret_cast<float4*>(out + i) = r;
}

// ---------------------------------------------------------------------------
extern "C" void kernel_launch(void* const* d_in, const int* in_sizes, int n_in,
                              void* d_out, int out_size, void* d_ws, size_t ws_size,
                              hipStream_t stream) {
  const float* x      = (const float*)d_in[0];
  const float* conv_w = (const float*)d_in[1];
  const float* conv_b = (const float*)d_in[2];
  const float* gamma  = (const float*)d_in[3];
  const float* beta   = (const float*)d_in[4];
  float* out = (float*)d_out;

  float* buf0 = (float*)d_ws;
  float* xn  = buf0;                               // NPTS*C
  float* xnT = buf0 + (size_t)NPTS_ * C_;          // NPTS*C
  float* h   = buf0;                               // overlay (xn/xnT dead)
  float* sq  = buf0 + 2 * (size_t)NPTS_ * C_;      // NPTS
  int*   nn9 = (int*)(sq + NPTS_);                 // NPTS*9
  float* psum = (float*)(nn9 + (size_t)NPTS_ * K_);
  float* pss  = psum + COUT_ * B_;
  float* af   = pss + COUT_ * B_;
  float* bfv  = af + COUT_;
  float* outpre = bfv + COUT_;                     // B*COUT*N

  hipLaunchKernelGGL(norm_kernel, dim3((NPTS_ + 255) / 256), dim3(256), 0, stream,
                     x, xn, xnT, sq);
  hipLaunchKernelGGL(knn_kernel, dim3(NPTS_), dim3(256), 0, stream,
                     xn, xnT, sq, nn9);
  hipLaunchKernelGGL(gather_kernel, dim3(C_, B_), dim3(256), 0, stream,
                     x, nn9, h);
  hipLaunchKernelGGL(conv_kernel, dim3(COUT_, B_), dim3(256), 0, stream,
                     h, conv_w, conv_b, outpre, psum, pss);
  hipLaunchKernelGGL(stats_kernel, dim3(COUT_), dim3(64), 0, stream,
                     psum, pss, gamma, beta, af, bfv);
  hipLaunchKernelGGL(act_kernel, dim3((B_ * COUT_ * N_) / (256 * 4)), dim3(256), 0, stream,
                     outpre, af, bfv, out);
}

// Round 8
// 476.928 us; speedup vs baseline: 1.7982x; 1.7982x over previous
//
#include <hip/hip_runtime.h>
#include <hip/hip_bf16.h>

#define B_    32
#define C_    192
#define N_    784
#define K_    9
#define COUT_ 384
#define NPTS_ (B_ * N_)   // 25088
#define QPB_  8           // queries per knn block

// ordered-uint transform: monotone map float -> uint
__device__ __forceinline__ unsigned int ford(float f) {
  unsigned int u = __float_as_uint(f);
  return u ^ ((u & 0x80000000u) ? 0xFFFFFFFFu : 0x80000000u);
}

// ---------------------------------------------------------------------------
// K1: fp32 norm (sequential), xn = x/norm (row + transposed), sq = pairwise
// ---------------------------------------------------------------------------
__global__ __launch_bounds__(256) void norm_kernel(
    const float* __restrict__ x, float* __restrict__ xn,
    float* __restrict__ xnT, float* __restrict__ sq) {
  int p = blockIdx.x * 256 + threadIdx.x;
  if (p >= NPTS_) return;
  int b = p / N_, n = p % N_;
  const float* xb = x + (size_t)b * C_ * N_ + n;
  float s = 0.f;
  for (int c = 0; c < C_; c++) {
    float v = xb[(size_t)c * N_];
    s = __fadd_rn(s, __fmul_rn(v, v));
  }
  float nrm = fmaxf(__fsqrt_rn(s), 1e-12f);
  float* xr = xn + (size_t)p * C_;
  float* xt = xnT + (size_t)b * C_ * N_ + n;
  float r0[8], r1[8];
  #pragma unroll
  for (int j = 0; j < 8; j++) {
    float a = __fdiv_rn(xb[(size_t)j * N_], nrm);
    xr[j] = a; xt[(size_t)j * N_] = a;
    r0[j] = __fmul_rn(a, a);
  }
  for (int i = 8; i < 96; i += 8) {
    #pragma unroll
    for (int j = 0; j < 8; j++) {
      float a = __fdiv_rn(xb[(size_t)(i + j) * N_], nrm);
      xr[i + j] = a; xt[(size_t)(i + j) * N_] = a;
      r0[j] = __fadd_rn(r0[j], __fmul_rn(a, a));
    }
  }
  #pragma unroll
  for (int j = 0; j < 8; j++) {
    float a = __fdiv_rn(xb[(size_t)(96 + j) * N_], nrm);
    xr[96 + j] = a; xt[(size_t)(96 + j) * N_] = a;
    r1[j] = __fmul_rn(a, a);
  }
  for (int i = 104; i < 192; i += 8) {
    #pragma unroll
    for (int j = 0; j < 8; j++) {
      float a = __fdiv_rn(xb[(size_t)(i + j) * N_], nrm);
      xr[i + j] = a; xt[(size_t)(i + j) * N_] = a;
      r1[j] = __fadd_rn(r1[j], __fmul_rn(a, a));
    }
  }
  float L = __fadd_rn(
      __fadd_rn(__fadd_rn(r0[0], r0[1]), __fadd_rn(r0[2], r0[3])),
      __fadd_rn(__fadd_rn(r0[4], r0[5]), __fadd_rn(r0[6], r0[7])));
  float R = __fadd_rn(
      __fadd_rn(__fadd_rn(r1[0], r1[1]), __fadd_rn(r1[2], r1[3])),
      __fadd_rn(__fadd_rn(r1[4], r1[5]), __fadd_rn(r1[6], r1[7])));
  sq[p] = __fadd_rn(L, R);
}

// ---------------------------------------------------------------------------
// K2: register-tiled KNN. Block = 256 thr = 4 waves, QPB_=8 queries/block.
//  Dot phase: thread t owns candidates {t, t+256, t+512, (t+768 if t<16)},
//  fma accumulation (sequential over c -> rounding within 1e-8 of np order).
//  Top-9 phase: one wave per query (waves 0..3 handle qi = w, then w+4),
//  stable (value, idx) argmin via 64-lane butterfly; knockout with +inf.
// ---------------------------------------------------------------------------
__global__ __launch_bounds__(256) void knn_kernel(
    const float* __restrict__ xn, const float* __restrict__ xnT,
    const float* __restrict__ sq, int* __restrict__ nn9) {
  int qt = blockIdx.x;
  int b  = blockIdx.y;
  int t  = threadIdx.x;
  int q0 = qt * QPB_;

  __shared__ float qv[QPB_][C_];   // 6 KB
  __shared__ float dl[QPB_][N_];   // 25.1 KB

  // load 8 contiguous query rows (8*192 floats)
  const float* qbase = xn + ((size_t)b * N_ + q0) * C_;
  for (int i = t; i < QPB_ * C_; i += 256) qv[i / C_][i % C_] = qbase[i];
  __syncthreads();

  const float* bT  = xnT + (size_t)b * C_ * N_;
  const float* sqb = sq + (size_t)b * N_;

  int m3 = (t < 16) ? (t + 768) : 783;   // clamped (result discarded t>=16)

  float acc[QPB_][4];
  #pragma unroll
  for (int qi = 0; qi < QPB_; qi++)
    #pragma unroll
    for (int j = 0; j < 4; j++) acc[qi][j] = 0.f;

  #pragma unroll 2
  for (int c = 0; c < C_; c++) {
    const float* col = bT + (size_t)c * N_;
    float c0 = col[t];
    float c1 = col[t + 256];
    float c2 = col[t + 512];
    float c3 = col[m3];
    #pragma unroll
    for (int qi = 0; qi < QPB_; qi++) {
      float q = qv[qi][c];
      acc[qi][0] = __fmaf_rn(q, c0, acc[qi][0]);
      acc[qi][1] = __fmaf_rn(q, c1, acc[qi][1]);
      acc[qi][2] = __fmaf_rn(q, c2, acc[qi][2]);
      acc[qi][3] = __fmaf_rn(q, c3, acc[qi][3]);
    }
  }

  float s0 = sqb[t], s1 = sqb[t + 256], s2 = sqb[t + 512], s3 = sqb[m3];
  #pragma unroll
  for (int qi = 0; qi < QPB_; qi++) {
    float sqpq = sqb[q0 + qi];
    dl[qi][t      ] = __fadd_rn(__fsub_rn(sqpq, __fmul_rn(2.0f, acc[qi][0])), s0);
    dl[qi][t + 256] = __fadd_rn(__fsub_rn(sqpq, __fmul_rn(2.0f, acc[qi][1])), s1);
    dl[qi][t + 512] = __fadd_rn(__fsub_rn(sqpq, __fmul_rn(2.0f, acc[qi][2])), s2);
    if (t < 16)
      dl[qi][t + 768] = __fadd_rn(__fsub_rn(sqpq, __fmul_rn(2.0f, acc[qi][3])), s3);
  }
  __syncthreads();

  int lane = t & 63;
  int w    = t >> 6;
  for (int rep = 0; rep < 2; rep++) {
    int qi = w + rep * 4;
    int* o = nn9 + ((size_t)b * N_ + q0 + qi) * K_;
    for (int kk = 0; kk < K_; kk++) {
      unsigned long long mk = ~0ull;
      for (int m = lane; m < N_; m += 64) {
        unsigned long long key =
            ((unsigned long long)ford(dl[qi][m]) << 10) | (unsigned int)m;
        mk = key < mk ? key : mk;
      }
      #pragma unroll
      for (int off = 1; off < 64; off <<= 1) {
        unsigned long long v = __shfl_xor(mk, off);
        mk = v < mk ? v : mk;
      }
      int widx = (int)(mk & 1023u);
      if (lane == 0) {
        o[kk] = widx;
        dl[qi][widx] = __int_as_float(0x7F800000);  // +inf knockout
      }
    }
  }
}

// ---------------------------------------------------------------------------
// K3: gather + max-relative -> h interleaved (B, 2C, N). One block per (c, b).
// ---------------------------------------------------------------------------
__global__ __launch_bounds__(256) void gather_kernel(
    const float* __restrict__ x, const int* __restrict__ nn9,
    float* __restrict__ h) {
  int c = blockIdx.x, b = blockIdx.y;
  int t = threadIdx.x;
  const float* row = x + ((size_t)b * C_ + c) * N_;
  const int* ib = nn9 + (size_t)b * N_ * K_;
  float* h0 = h + ((size_t)b * (2 * C_) + 2 * c) * N_;
  for (int n = t; n < N_; n += 256) {
    float xv = row[n];
    float mx = -1e30f;
    #pragma unroll
    for (int k = 0; k < K_; k++) {
      int idx = ib[n * K_ + k];
      mx = fmaxf(mx, row[idx]);
    }
    h0[n] = xv;
    h0[N_ + n] = mx - xv;
  }
}

// ---------------------------------------------------------------------------
// K4: grouped 1x1 conv + bias, one block per (co, b); BN partial sums.
// ---------------------------------------------------------------------------
__global__ __launch_bounds__(256) void conv_kernel(
    const float* __restrict__ h, const float* __restrict__ w,
    const float* __restrict__ bias, float* __restrict__ outpre,
    float* __restrict__ psum, float* __restrict__ pss) {
  int co = blockIdx.x, b = blockIdx.y;
  int g = co / 96;
  int t = threadIdx.x;
  __shared__ float wrow[96];
  __shared__ float rs[4], rss[4];
  if (t < 96) wrow[t] = w[(size_t)co * 96 + t];
  __syncthreads();

  float s = 0.f, s2 = 0.f;
  const float* hb = h + ((size_t)b * (2 * C_) + (size_t)g * 96) * N_;
  float bv = bias[co];
  float* orow = outpre + ((size_t)b * COUT_ + co) * N_;
  for (int n4 = t; n4 < N_ / 4; n4 += 256) {
    float4 acc = {bv, bv, bv, bv};
    for (int i = 0; i < 96; i++) {
      float wv = wrow[i];
      float4 hv = *(const float4*)(hb + (size_t)i * N_ + n4 * 4);
      acc.x += wv * hv.x; acc.y += wv * hv.y;
      acc.z += wv * hv.z; acc.w += wv * hv.w;
    }
    *(float4*)(orow + n4 * 4) = acc;
    s += acc.x + acc.y + acc.z + acc.w;
    s2 += acc.x * acc.x + acc.y * acc.y + acc.z * acc.z + acc.w * acc.w;
  }
  #pragma unroll
  for (int off = 1; off < 64; off <<= 1) {
    s += __shfl_xor(s, off);
    s2 += __shfl_xor(s2, off);
  }
  if ((t & 63) == 0) { rs[t >> 6] = s; rss[t >> 6] = s2; }
  __syncthreads();
  if (t == 0) {
    psum[(size_t)co * B_ + b] = rs[0] + rs[1] + rs[2] + rs[3];
    pss [(size_t)co * B_ + b] = rss[0] + rss[1] + rss[2] + rss[3];
  }
}

// ---------------------------------------------------------------------------
// K5: finalize BN stats -> per-channel affine a, b
// ---------------------------------------------------------------------------
__global__ __launch_bounds__(64) void stats_kernel(
    const float* __restrict__ psum, const float* __restrict__ pss,
    const float* __restrict__ gamma, const float* __restrict__ beta,
    float* __restrict__ af, float* __restrict__ bf) {
  int co = blockIdx.x;
  int l = threadIdx.x;
  double s = 0.0, s2 = 0.0;
  for (int i = l; i < B_; i += 64) {
    s  += (double)psum[(size_t)co * B_ + i];
    s2 += (double)pss [(size_t)co * B_ + i];
  }
  #pragma unroll
  for (int o = 32; o > 0; o >>= 1) { s += __shfl_xor(s, o); s2 += __shfl_xor(s2, o); }
  if (l == 0) {
    const double cnt = (double)NPTS_;
    double mean = s / cnt;
    double var  = s2 / cnt - mean * mean;
    double rstd = 1.0 / sqrt(var + 1e-5);
    double a = (double)gamma[co] * rstd;
    af[co] = (float)a;
    bf[co] = (float)((double)beta[co] - mean * a);
  }
}

// ---------------------------------------------------------------------------
// K6: BN affine + exact GELU + fp32 store
// ---------------------------------------------------------------------------
__global__ __launch_bounds__(256) void act_kernel(
    const float* __restrict__ outpre, const float* __restrict__ af,
    const float* __restrict__ bf, float* __restrict__ out) {
  size_t i = ((size_t)blockIdx.x * 256 + threadIdx.x) * 4;
  int co = (int)((i / N_) % COUT_);
  float a = af[co], c = bf[co];
  float4 v = *(const float4*)(outpre + i);
  float y0 = a * v.x + c, y1 = a * v.y + c, y2 = a * v.z + c, y3 = a * v.w + c;
  const float is2 = 0.70710678118654752f;
  float4 r;
  r.x = 0.5f * y0 * (1.0f + erff(y0 * is2));
  r.y = 0.5f * y1 * (1.0f + erff(y1 * is2));
  r.z = 0.5f * y2 * (1.0f + erff(y2 * is2));
  r.w = 0.5f * y3 * (1.0f + erff(y3 * is2));
  *reinterpret_cast<float4*>(out + i) = r;
}

// ---------------------------------------------------------------------------
extern "C" void kernel_launch(void* const* d_in, const int* in_sizes, int n_in,
                              void* d_out, int out_size, void* d_ws, size_t ws_size,
                              hipStream_t stream) {
  const float* x      = (const float*)d_in[0];
  const float* conv_w = (const float*)d_in[1];
  const float* conv_b = (const float*)d_in[2];
  const float* gamma  = (const float*)d_in[3];
  const float* beta   = (const float*)d_in[4];
  float* out = (float*)d_out;

  float* buf0 = (float*)d_ws;
  float* xn  = buf0;                               // NPTS*C
  float* xnT = buf0 + (size_t)NPTS_ * C_;          // NPTS*C
  float* h   = buf0;                               // overlay (xn/xnT dead)
  float* sq  = buf0 + 2 * (size_t)NPTS_ * C_;      // NPTS
  int*   nn9 = (int*)(sq + NPTS_);                 // NPTS*9
  float* psum = (float*)(nn9 + (size_t)NPTS_ * K_);
  float* pss  = psum + COUT_ * B_;
  float* af   = pss + COUT_ * B_;
  float* bfv  = af + COUT_;
  float* outpre = bfv + COUT_;                     // B*COUT*N

  hipLaunchKernelGGL(norm_kernel, dim3((NPTS_ + 255) / 256), dim3(256), 0, stream,
                     x, xn, xnT, sq);
  hipLaunchKernelGGL(knn_kernel, dim3(N_ / QPB_, B_), dim3(256), 0, stream,
                     xn, xnT, sq, nn9);
  hipLaunchKernelGGL(gather_kernel, dim3(C_, B_), dim3(256), 0, stream,
                     x, nn9, h);
  hipLaunchKernelGGL(conv_kernel, dim3(COUT_, B_), dim3(256), 0, stream,
                     h, conv_w, conv_b, outpre, psum, pss);
  hipLaunchKernelGGL(stats_kernel, dim3(COUT_), dim3(64), 0, stream,
                     psum, pss, gamma, beta, af, bfv);
  hipLaunchKernelGGL(act_kernel, dim3((B_ * COUT_ * N_) / (256 * 4)), dim3(256), 0, stream,
                     outpre, af, bfv, out);
}

// Round 9
// 463.118 us; speedup vs baseline: 1.8519x; 1.0298x over previous
//
#include <hip/hip_runtime.h>
#include <hip/hip_bf16.h>

#define B_    32
#define C_    192
#define N_    784
#define NP_   1024        // padded candidate dim
#define K_    9
#define COUT_ 384
#define NPTS_ (B_ * N_)   // 25088
#define QPB_  8           // queries per knn block

// ordered-uint transform: monotone map float -> uint
__device__ __forceinline__ unsigned int ford(float f) {
  unsigned int u = __float_as_uint(f);
  return u ^ ((u & 0x80000000u) ? 0xFFFFFFFFu : 0x80000000u);
}

// ---------------------------------------------------------------------------
// K0: write padding region of xnT (zeros) and sqp (+1e30) — every launch,
// since ws is not re-poisoned between replays.
// ---------------------------------------------------------------------------
__global__ __launch_bounds__(256) void pad_kernel(
    float* __restrict__ xnT, float* __restrict__ sqp) {
  int i = blockIdx.x * 256 + threadIdx.x;
  const int npad = B_ * C_ * (NP_ - N_);
  if (i < npad) {
    int j  = i % (NP_ - N_);
    int cc = (i / (NP_ - N_)) % C_;
    int bb = i / ((NP_ - N_) * C_);
    xnT[((size_t)bb * C_ + cc) * NP_ + N_ + j] = 0.f;
  }
  int s = i - npad;
  if (s >= 0 && s < B_ * (NP_ - N_)) {
    int j = s % (NP_ - N_), bb = s / (NP_ - N_);
    sqp[(size_t)bb * NP_ + N_ + j] = 1e30f;
  }
}

// ---------------------------------------------------------------------------
// K1: fp32 norm (sequential), xn = x/norm (row-major + padded transposed),
//     sq = numpy pairwise (96/96, 8 accs) -> sqp[b][n]
// ---------------------------------------------------------------------------
__global__ __launch_bounds__(256) void norm_kernel(
    const float* __restrict__ x, float* __restrict__ xn,
    float* __restrict__ xnT, float* __restrict__ sqp) {
  int p = blockIdx.x * 256 + threadIdx.x;
  if (p >= NPTS_) return;
  int b = p / N_, n = p % N_;
  const float* xb = x + (size_t)b * C_ * N_ + n;
  float s = 0.f;
  for (int c = 0; c < C_; c++) {
    float v = xb[(size_t)c * N_];
    s = __fadd_rn(s, __fmul_rn(v, v));
  }
  float nrm = fmaxf(__fsqrt_rn(s), 1e-12f);
  float* xr = xn + (size_t)p * C_;
  float* xt = xnT + (size_t)b * C_ * NP_ + n;
  float r0[8], r1[8];
  #pragma unroll
  for (int j = 0; j < 8; j++) {
    float a = __fdiv_rn(xb[(size_t)j * N_], nrm);
    xr[j] = a; xt[(size_t)j * NP_] = a;
    r0[j] = __fmul_rn(a, a);
  }
  for (int i = 8; i < 96; i += 8) {
    #pragma unroll
    for (int j = 0; j < 8; j++) {
      float a = __fdiv_rn(xb[(size_t)(i + j) * N_], nrm);
      xr[i + j] = a; xt[(size_t)(i + j) * NP_] = a;
      r0[j] = __fadd_rn(r0[j], __fmul_rn(a, a));
    }
  }
  #pragma unroll
  for (int j = 0; j < 8; j++) {
    float a = __fdiv_rn(xb[(size_t)(96 + j) * N_], nrm);
    xr[96 + j] = a; xt[(size_t)(96 + j) * NP_] = a;
    r1[j] = __fmul_rn(a, a);
  }
  for (int i = 104; i < 192; i += 8) {
    #pragma unroll
    for (int j = 0; j < 8; j++) {
      float a = __fdiv_rn(xb[(size_t)(i + j) * N_], nrm);
      xr[i + j] = a; xt[(size_t)(i + j) * NP_] = a;
      r1[j] = __fadd_rn(r1[j], __fmul_rn(a, a));
    }
  }
  float L = __fadd_rn(
      __fadd_rn(__fadd_rn(r0[0], r0[1]), __fadd_rn(r0[2], r0[3])),
      __fadd_rn(__fadd_rn(r0[4], r0[5]), __fadd_rn(r0[6], r0[7])));
  float R = __fadd_rn(
      __fadd_rn(__fadd_rn(r1[0], r1[1]), __fadd_rn(r1[2], r1[3])),
      __fadd_rn(__fadd_rn(r1[4], r1[5]), __fadd_rn(r1[6], r1[7])));
  sqp[(size_t)b * NP_ + n] = __fadd_rn(L, R);
}

// ---------------------------------------------------------------------------
// K2: register-tiled KNN (padded candidates).
//  Thread t owns candidates {4t..4t+3} via ONE dwordx4 per c;
//  query tile transposed in LDS -> 2 ds_read_b128 per c; 32 fma per c.
//  Per-candidate fma chain order identical to previous round.
// ---------------------------------------------------------------------------
__global__ __launch_bounds__(256) void knn_kernel(
    const float* __restrict__ xn, const float* __restrict__ xnT,
    const float* __restrict__ sqp, int* __restrict__ nn9) {
  int qt = blockIdx.x;
  int b  = blockIdx.y;
  int t  = threadIdx.x;
  int q0 = qt * QPB_;

  __shared__ float qv[C_][QPB_];   // 6 KB, transposed
  __shared__ float dl[QPB_][NP_];  // 32 KB

  const float* qbase = xn + ((size_t)b * N_ + q0) * C_;
  for (int i = t; i < QPB_ * C_; i += 256) qv[i % C_][i / C_] = qbase[i];
  __syncthreads();

  const float* bT  = xnT + (size_t)b * C_ * NP_;
  const float* sqb = sqp + (size_t)b * NP_;

  float acc[QPB_][4];
  #pragma unroll
  for (int qi = 0; qi < QPB_; qi++)
    #pragma unroll
    for (int j = 0; j < 4; j++) acc[qi][j] = 0.f;

  #pragma unroll 2
  for (int c = 0; c < C_; c++) {
    float4 cv = *((const float4*)(bT + (size_t)c * NP_) + t);
    float4 qa = *(const float4*)(&qv[c][0]);
    float4 qb = *(const float4*)(&qv[c][4]);
    float qarr[QPB_] = {qa.x, qa.y, qa.z, qa.w, qb.x, qb.y, qb.z, qb.w};
    #pragma unroll
    for (int qi = 0; qi < QPB_; qi++) {
      acc[qi][0] = __fmaf_rn(qarr[qi], cv.x, acc[qi][0]);
      acc[qi][1] = __fmaf_rn(qarr[qi], cv.y, acc[qi][1]);
      acc[qi][2] = __fmaf_rn(qarr[qi], cv.z, acc[qi][2]);
      acc[qi][3] = __fmaf_rn(qarr[qi], cv.w, acc[qi][3]);
    }
  }

  float4 sv = *((const float4*)sqb + t);
  #pragma unroll
  for (int qi = 0; qi < QPB_; qi++) {
    float sqq = sqb[q0 + qi];
    float4 dv;
    dv.x = __fadd_rn(__fsub_rn(sqq, __fmul_rn(2.0f, acc[qi][0])), sv.x);
    dv.y = __fadd_rn(__fsub_rn(sqq, __fmul_rn(2.0f, acc[qi][1])), sv.y);
    dv.z = __fadd_rn(__fsub_rn(sqq, __fmul_rn(2.0f, acc[qi][2])), sv.z);
    dv.w = __fadd_rn(__fsub_rn(sqq, __fmul_rn(2.0f, acc[qi][3])), sv.w);
    *(float4*)(&dl[qi][4 * t]) = dv;
  }
  __syncthreads();

  int lane = t & 63;
  int w    = t >> 6;
  for (int rep = 0; rep < 2; rep++) {
    int qi = w + rep * 4;
    int* o = nn9 + ((size_t)b * N_ + q0 + qi) * K_;
    for (int kk = 0; kk < K_; kk++) {
      unsigned long long mk = ~0ull;
      #pragma unroll
      for (int it = 0; it < NP_ / 64; it++) {
        int m = lane + it * 64;
        unsigned long long key =
            ((unsigned long long)ford(dl[qi][m]) << 10) | (unsigned int)m;
        mk = key < mk ? key : mk;
      }
      #pragma unroll
      for (int off = 1; off < 64; off <<= 1) {
        unsigned long long v = __shfl_xor(mk, off);
        mk = v < mk ? v : mk;
      }
      int widx = (int)(mk & 1023u);
      if (lane == 0) {
        o[kk] = widx;
        dl[qi][widx] = __int_as_float(0x7F800000);  // +inf knockout
      }
    }
  }
}

// ---------------------------------------------------------------------------
// K3: gather + max-relative -> h interleaved (B, 2C, N). One block per (c, b).
// ---------------------------------------------------------------------------
__global__ __launch_bounds__(256) void gather_kernel(
    const float* __restrict__ x, const int* __restrict__ nn9,
    float* __restrict__ h) {
  int c = blockIdx.x, b = blockIdx.y;
  int t = threadIdx.x;
  const float* row = x + ((size_t)b * C_ + c) * N_;
  const int* ib = nn9 + (size_t)b * N_ * K_;
  float* h0 = h + ((size_t)b * (2 * C_) + 2 * c) * N_;
  for (int n = t; n < N_; n += 256) {
    float xv = row[n];
    float mx = -1e30f;
    #pragma unroll
    for (int k = 0; k < K_; k++) {
      int idx = ib[n * K_ + k];
      mx = fmaxf(mx, row[idx]);
    }
    h0[n] = xv;
    h0[N_ + n] = mx - xv;
  }
}

// ---------------------------------------------------------------------------
// K4: grouped 1x1 conv + bias, one block per (co, b); BN partial sums.
// ---------------------------------------------------------------------------
__global__ __launch_bounds__(256) void conv_kernel(
    const float* __restrict__ h, const float* __restrict__ w,
    const float* __restrict__ bias, float* __restrict__ outpre,
    float* __restrict__ psum, float* __restrict__ pss) {
  int co = blockIdx.x, b = blockIdx.y;
  int g = co / 96;
  int t = threadIdx.x;
  __shared__ float wrow[96];
  __shared__ float rs[4], rss[4];
  if (t < 96) wrow[t] = w[(size_t)co * 96 + t];
  __syncthreads();

  float s = 0.f, s2 = 0.f;
  const float* hb = h + ((size_t)b * (2 * C_) + (size_t)g * 96) * N_;
  float bv = bias[co];
  float* orow = outpre + ((size_t)b * COUT_ + co) * N_;
  for (int n4 = t; n4 < N_ / 4; n4 += 256) {
    float4 acc = {bv, bv, bv, bv};
    for (int i = 0; i < 96; i++) {
      float wv = wrow[i];
      float4 hv = *(const float4*)(hb + (size_t)i * N_ + n4 * 4);
      acc.x += wv * hv.x; acc.y += wv * hv.y;
      acc.z += wv * hv.z; acc.w += wv * hv.w;
    }
    *(float4*)(orow + n4 * 4) = acc;
    s += acc.x + acc.y + acc.z + acc.w;
    s2 += acc.x * acc.x + acc.y * acc.y + acc.z * acc.z + acc.w * acc.w;
  }
  #pragma unroll
  for (int off = 1; off < 64; off <<= 1) {
    s += __shfl_xor(s, off);
    s2 += __shfl_xor(s2, off);
  }
  if ((t & 63) == 0) { rs[t >> 6] = s; rss[t >> 6] = s2; }
  __syncthreads();
  if (t == 0) {
    psum[(size_t)co * B_ + b] = rs[0] + rs[1] + rs[2] + rs[3];
    pss [(size_t)co * B_ + b] = rss[0] + rss[1] + rss[2] + rss[3];
  }
}

// ---------------------------------------------------------------------------
// K5: finalize BN stats -> per-channel affine a, b
// ---------------------------------------------------------------------------
__global__ __launch_bounds__(64) void stats_kernel(
    const float* __restrict__ psum, const float* __restrict__ pss,
    const float* __restrict__ gamma, const float* __restrict__ beta,
    float* __restrict__ af, float* __restrict__ bf) {
  int co = blockIdx.x;
  int l = threadIdx.x;
  double s = 0.0, s2 = 0.0;
  for (int i = l; i < B_; i += 64) {
    s  += (double)psum[(size_t)co * B_ + i];
    s2 += (double)pss [(size_t)co * B_ + i];
  }
  #pragma unroll
  for (int o = 32; o > 0; o >>= 1) { s += __shfl_xor(s, o); s2 += __shfl_xor(s2, o); }
  if (l == 0) {
    const double cnt = (double)NPTS_;
    double mean = s / cnt;
    double var  = s2 / cnt - mean * mean;
    double rstd = 1.0 / sqrt(var + 1e-5);
    double a = (double)gamma[co] * rstd;
    af[co] = (float)a;
    bf[co] = (float)((double)beta[co] - mean * a);
  }
}

// ---------------------------------------------------------------------------
// K6: BN affine + exact GELU + fp32 store
// ---------------------------------------------------------------------------
__global__ __launch_bounds__(256) void act_kernel(
    const float* __restrict__ outpre, const float* __restrict__ af,
    const float* __restrict__ bf, float* __restrict__ out) {
  size_t i = ((size_t)blockIdx.x * 256 + threadIdx.x) * 4;
  int co = (int)((i / N_) % COUT_);
  float a = af[co], c = bf[co];
  float4 v = *(const float4*)(outpre + i);
  float y0 = a * v.x + c, y1 = a * v.y + c, y2 = a * v.z + c, y3 = a * v.w + c;
  const float is2 = 0.70710678118654752f;
  float4 r;
  r.x = 0.5f * y0 * (1.0f + erff(y0 * is2));
  r.y = 0.5f * y1 * (1.0f + erff(y1 * is2));
  r.z = 0.5f * y2 * (1.0f + erff(y2 * is2));
  r.w = 0.5f * y3 * (1.0f + erff(y3 * is2));
  *reinterpret_cast<float4*>(out + i) = r;
}

// ---------------------------------------------------------------------------
extern "C" void kernel_launch(void* const* d_in, const int* in_sizes, int n_in,
                              void* d_out, int out_size, void* d_ws, size_t ws_size,
                              hipStream_t stream) {
  const float* x      = (const float*)d_in[0];
  const float* conv_w = (const float*)d_in[1];
  const float* conv_b = (const float*)d_in[2];
  const float* gamma  = (const float*)d_in[3];
  const float* beta   = (const float*)d_in[4];
  float* out = (float*)d_out;

  // ws layout (peak 78.1 MB, <= prior round's proven 78.2 MB):
  //  phase A (norm+knn):  xn [0,4.82M) | xnT [4.82M,11.11M) | sqp [11.11M,11.14M)
  //  phase B (gather+):   h [0,9.63M) | outpre [9.63M,19.27M)
  //  persistent:          nn9 @19.27M | psum/pss/af/bf after
  float* buf0 = (float*)d_ws;
  float* xn   = buf0;                                    // NPTS*C
  float* xnT  = buf0 + (size_t)NPTS_ * C_;               // B*C*NP
  float* sqp  = xnT + (size_t)B_ * C_ * NP_;             // B*NP
  float* h    = buf0;                                    // overlay
  float* outpre = buf0 + (size_t)B_ * 2 * C_ * N_;       // after h
  int*   nn9  = (int*)(outpre + (size_t)B_ * COUT_ * N_);// NPTS*9
  float* psum = (float*)(nn9 + (size_t)NPTS_ * K_);
  float* pss  = psum + COUT_ * B_;
  float* af   = pss + COUT_ * B_;
  float* bfv  = af + COUT_;

  const int npad_total = B_ * C_ * (NP_ - N_) + B_ * (NP_ - N_);
  hipLaunchKernelGGL(pad_kernel, dim3((npad_total + 255) / 256), dim3(256), 0, stream,
                     xnT, sqp);
  hipLaunchKernelGGL(norm_kernel, dim3((NPTS_ + 255) / 256), dim3(256), 0, stream,
                     x, xn, xnT, sqp);
  hipLaunchKernelGGL(knn_kernel, dim3(N_ / QPB_, B_), dim3(256), 0, stream,
                     xn, xnT, sqp, nn9);
  hipLaunchKernelGGL(gather_kernel, dim3(C_, B_), dim3(256), 0, stream,
                     x, nn9, h);
  hipLaunchKernelGGL(conv_kernel, dim3(COUT_, B_), dim3(256), 0, stream,
                     h, conv_w, conv_b, outpre, psum, pss);
  hipLaunchKernelGGL(stats_kernel, dim3(COUT_), dim3(64), 0, stream,
                     psum, pss, gamma, beta, af, bfv);
  hipLaunchKernelGGL(act_kernel, dim3((B_ * COUT_ * N_) / (256 * 4)), dim3(256), 0, stream,
                     outpre, af, bfv, out);
}

// Round 10
// 360.107 us; speedup vs baseline: 2.3816x; 1.2861x over previous
//
#include <hip/hip_runtime.h>
#include <hip/hip_bf16.h>

#define B_    32
#define C_    192
#define N_    784
#define NP_   1024        // padded candidate dim
#define K_    9
#define COUT_ 384
#define NPTS_ (B_ * N_)   // 25088
#define QPB_  8           // queries per knn block
#define NTILES_ 224       // 32 b * 7 ntiles

// ordered-uint transform: monotone map float -> uint
__device__ __forceinline__ unsigned int ford(float f) {
  unsigned int u = __float_as_uint(f);
  return u ^ ((u & 0x80000000u) ? 0xFFFFFFFFu : 0x80000000u);
}

// ---------------------------------------------------------------------------
// K0: write padding region of xnT (zeros) and sqp (+1e30) — every launch.
// ---------------------------------------------------------------------------
__global__ __launch_bounds__(256) void pad_kernel(
    float* __restrict__ xnT, float* __restrict__ sqp) {
  int i = blockIdx.x * 256 + threadIdx.x;
  const int npad = B_ * C_ * (NP_ - N_);
  if (i < npad) {
    int j  = i % (NP_ - N_);
    int cc = (i / (NP_ - N_)) % C_;
    int bb = i / ((NP_ - N_) * C_);
    xnT[((size_t)bb * C_ + cc) * NP_ + N_ + j] = 0.f;
  }
  int s = i - npad;
  if (s >= 0 && s < B_ * (NP_ - N_)) {
    int j = s % (NP_ - N_), bb = s / (NP_ - N_);
    sqp[(size_t)bb * NP_ + N_ + j] = 1e30f;
  }
}

// ---------------------------------------------------------------------------
// K1: fp32 norm (sequential), xn = x/norm (row-major + padded transposed),
//     sq = numpy pairwise (96/96, 8 accs) -> sqp[b][n]
// ---------------------------------------------------------------------------
__global__ __launch_bounds__(256) void norm_kernel(
    const float* __restrict__ x, float* __restrict__ xn,
    float* __restrict__ xnT, float* __restrict__ sqp) {
  int p = blockIdx.x * 256 + threadIdx.x;
  if (p >= NPTS_) return;
  int b = p / N_, n = p % N_;
  const float* xb = x + (size_t)b * C_ * N_ + n;
  float s = 0.f;
  for (int c = 0; c < C_; c++) {
    float v = xb[(size_t)c * N_];
    s = __fadd_rn(s, __fmul_rn(v, v));
  }
  float nrm = fmaxf(__fsqrt_rn(s), 1e-12f);
  float* xr = xn + (size_t)p * C_;
  float* xt = xnT + (size_t)b * C_ * NP_ + n;
  float r0[8], r1[8];
  #pragma unroll
  for (int j = 0; j < 8; j++) {
    float a = __fdiv_rn(xb[(size_t)j * N_], nrm);
    xr[j] = a; xt[(size_t)j * NP_] = a;
    r0[j] = __fmul_rn(a, a);
  }
  for (int i = 8; i < 96; i += 8) {
    #pragma unroll
    for (int j = 0; j < 8; j++) {
      float a = __fdiv_rn(xb[(size_t)(i + j) * N_], nrm);
      xr[i + j] = a; xt[(size_t)(i + j) * NP_] = a;
      r0[j] = __fadd_rn(r0[j], __fmul_rn(a, a));
    }
  }
  #pragma unroll
  for (int j = 0; j < 8; j++) {
    float a = __fdiv_rn(xb[(size_t)(96 + j) * N_], nrm);
    xr[96 + j] = a; xt[(size_t)(96 + j) * NP_] = a;
    r1[j] = __fmul_rn(a, a);
  }
  for (int i = 104; i < 192; i += 8) {
    #pragma unroll
    for (int j = 0; j < 8; j++) {
      float a = __fdiv_rn(xb[(size_t)(i + j) * N_], nrm);
      xr[i + j] = a; xt[(size_t)(i + j) * NP_] = a;
      r1[j] = __fadd_rn(r1[j], __fmul_rn(a, a));
    }
  }
  float L = __fadd_rn(
      __fadd_rn(__fadd_rn(r0[0], r0[1]), __fadd_rn(r0[2], r0[3])),
      __fadd_rn(__fadd_rn(r0[4], r0[5]), __fadd_rn(r0[6], r0[7])));
  float R = __fadd_rn(
      __fadd_rn(__fadd_rn(r1[0], r1[1]), __fadd_rn(r1[2], r1[3])),
      __fadd_rn(__fadd_rn(r1[4], r1[5]), __fadd_rn(r1[6], r1[7])));
  sqp[(size_t)b * NP_ + n] = __fadd_rn(L, R);
}

// ---------------------------------------------------------------------------
// K2: register-tiled KNN; selection in 2 groups of 4 queries to halve LDS
// (dl 16 KB + qv 6 KB -> 7 blocks/CU). Dot phase byte-identical to R9.
// ---------------------------------------------------------------------------
__global__ __launch_bounds__(256) void knn_kernel(
    const float* __restrict__ xn, const float* __restrict__ xnT,
    const float* __restrict__ sqp, int* __restrict__ nn9) {
  int qt = blockIdx.x;
  int b  = blockIdx.y;
  int t  = threadIdx.x;
  int q0 = qt * QPB_;

  __shared__ float qv[C_][QPB_];   // 6 KB, transposed
  __shared__ float dl[4][NP_];     // 16 KB (half of the 8 queries at a time)

  const float* qbase = xn + ((size_t)b * N_ + q0) * C_;
  for (int i = t; i < QPB_ * C_; i += 256) qv[i % C_][i / C_] = qbase[i];
  __syncthreads();

  const float* bT  = xnT + (size_t)b * C_ * NP_;
  const float* sqb = sqp + (size_t)b * NP_;

  float acc[QPB_][4];
  #pragma unroll
  for (int qi = 0; qi < QPB_; qi++)
    #pragma unroll
    for (int j = 0; j < 4; j++) acc[qi][j] = 0.f;

  #pragma unroll 4
  for (int c = 0; c < C_; c++) {
    float4 cv = *((const float4*)(bT + (size_t)c * NP_) + t);
    float4 qa = *(const float4*)(&qv[c][0]);
    float4 qb = *(const float4*)(&qv[c][4]);
    float qarr[QPB_] = {qa.x, qa.y, qa.z, qa.w, qb.x, qb.y, qb.z, qb.w};
    #pragma unroll
    for (int qi = 0; qi < QPB_; qi++) {
      acc[qi][0] = __fmaf_rn(qarr[qi], cv.x, acc[qi][0]);
      acc[qi][1] = __fmaf_rn(qarr[qi], cv.y, acc[qi][1]);
      acc[qi][2] = __fmaf_rn(qarr[qi], cv.z, acc[qi][2]);
      acc[qi][3] = __fmaf_rn(qarr[qi], cv.w, acc[qi][3]);
    }
  }

  float4 sv = *((const float4*)sqb + t);
  int lane = t & 63;
  int w    = t >> 6;

  for (int grp = 0; grp < 2; grp++) {
    #pragma unroll
    for (int qj = 0; qj < 4; qj++) {
      int qi = grp * 4 + qj;
      float sqq = sqb[q0 + qi];
      float4 dv;
      dv.x = __fadd_rn(__fsub_rn(sqq, __fmul_rn(2.0f, acc[qi][0])), sv.x);
      dv.y = __fadd_rn(__fsub_rn(sqq, __fmul_rn(2.0f, acc[qi][1])), sv.y);
      dv.z = __fadd_rn(__fsub_rn(sqq, __fmul_rn(2.0f, acc[qi][2])), sv.z);
      dv.w = __fadd_rn(__fsub_rn(sqq, __fmul_rn(2.0f, acc[qi][3])), sv.w);
      *(float4*)(&dl[qj][4 * t]) = dv;
    }
    __syncthreads();
    // wave w selects for query grp*4 + w
    int* o = nn9 + ((size_t)b * N_ + q0 + grp * 4 + w) * K_;
    for (int kk = 0; kk < K_; kk++) {
      unsigned long long mk = ~0ull;
      #pragma unroll
      for (int it = 0; it < NP_ / 64; it++) {
        int m = lane + it * 64;
        unsigned long long key =
            ((unsigned long long)ford(dl[w][m]) << 10) | (unsigned int)m;
        mk = key < mk ? key : mk;
      }
      #pragma unroll
      for (int off = 1; off < 64; off <<= 1) {
        unsigned long long v = __shfl_xor(mk, off);
        mk = v < mk ? v : mk;
      }
      int widx = (int)(mk & 1023u);
      if (lane == 0) {
        o[kk] = widx;
        dl[w][widx] = __int_as_float(0x7F800000);  // +inf knockout
      }
    }
    __syncthreads();  // selection done before dl reuse
  }
}

// ---------------------------------------------------------------------------
// K3: FUSED gather + max-relative + grouped 1x1 conv + BN partial sums.
// grid = (7 ntiles, 8 = g*2+half, 32 b), 256 thr. h never materialized.
// ---------------------------------------------------------------------------
__global__ __launch_bounds__(256) void fconv_kernel(
    const float* __restrict__ x, const int* __restrict__ nn9,
    const float* __restrict__ w, const float* __restrict__ bias,
    float* __restrict__ outpre, float* __restrict__ psum,
    float* __restrict__ pss) {
  int nt = blockIdx.x;
  int gh = blockIdx.y;
  int b  = blockIdx.z;
  int g = gh >> 1, half = gh & 1;
  int n0 = nt * 112;
  int t = threadIdx.x;

  __shared__ float Wl[48][97];            // 18.6 KB
  __shared__ float Hl[96][112];           // 43.0 KB
  __shared__ unsigned short Il[112][K_];  // 2.0 KB

  const float* wsrc = w + (size_t)(g * 96 + half * 48) * 96;
  for (int i = t; i < 48 * 96; i += 256) Wl[i / 96][i % 96] = wsrc[i];
  const int* isrc = nn9 + ((size_t)b * N_ + n0) * K_;
  for (int i = t; i < 112 * K_; i += 256)
    Il[i / K_][i % K_] = (unsigned short)isrc[i];
  __syncthreads();

  const float* xb = x + (size_t)b * C_ * N_;
  for (int pos = t; pos < 48 * 112; pos += 256) {
    int cl = pos / 112, nl = pos % 112;
    const float* row = xb + (size_t)(g * 48 + cl) * N_;
    float xv = row[n0 + nl];
    float mx = -1e30f;
    #pragma unroll
    for (int k = 0; k < K_; k++) mx = fmaxf(mx, row[Il[nl][k]]);
    Hl[2 * cl][nl]     = xv;
    Hl[2 * cl + 1][nl] = mx - xv;
  }
  __syncthreads();

  int tx = t & 15, ty = t >> 4;
  float o[3][7];
  #pragma unroll
  for (int i = 0; i < 3; i++)
    #pragma unroll
    for (int j = 0; j < 7; j++) o[i][j] = 0.f;

  for (int k = 0; k < 96; k++) {
    float w0 = Wl[ty * 3 + 0][k];
    float w1 = Wl[ty * 3 + 1][k];
    float w2 = Wl[ty * 3 + 2][k];
    #pragma unroll
    for (int j = 0; j < 7; j++) {
      float hv = Hl[k][tx * 7 + j];
      o[0][j] = __fmaf_rn(w0, hv, o[0][j]);
      o[1][j] = __fmaf_rn(w1, hv, o[1][j]);
      o[2][j] = __fmaf_rn(w2, hv, o[2][j]);
    }
  }

  #pragma unroll
  for (int i = 0; i < 3; i++) {
    int co = g * 96 + half * 48 + ty * 3 + i;
    float bv = bias[co];
    float s = 0.f, s2 = 0.f;
    float* orow = outpre + ((size_t)b * COUT_ + co) * N_ + n0 + tx * 7;
    #pragma unroll
    for (int j = 0; j < 7; j++) {
      float v = o[i][j] + bv;
      orow[j] = v;
      s += v; s2 += v * v;
    }
    #pragma unroll
    for (int off = 1; off < 16; off <<= 1) {
      s  += __shfl_xor(s, off);
      s2 += __shfl_xor(s2, off);
    }
    if (tx == 0) {
      int tidx = b * 7 + nt;
      psum[co * NTILES_ + tidx] = s;
      pss [co * NTILES_ + tidx] = s2;
    }
  }
}

// ---------------------------------------------------------------------------
// K4: finalize BN stats -> per-channel affine a, b
// ---------------------------------------------------------------------------
__global__ __launch_bounds__(64) void stats_kernel(
    const float* __restrict__ psum, const float* __restrict__ pss,
    const float* __restrict__ gamma, const float* __restrict__ beta,
    float* __restrict__ af, float* __restrict__ bf) {
  int co = blockIdx.x;
  int l = threadIdx.x;
  double s = 0.0, s2 = 0.0;
  for (int i = l; i < NTILES_; i += 64) {
    s  += (double)psum[co * NTILES_ + i];
    s2 += (double)pss [co * NTILES_ + i];
  }
  #pragma unroll
  for (int o = 32; o > 0; o >>= 1) { s += __shfl_xor(s, o); s2 += __shfl_xor(s2, o); }
  if (l == 0) {
    const double cnt = (double)NPTS_;
    double mean = s / cnt;
    double var  = s2 / cnt - mean * mean;
    double rstd = 1.0 / sqrt(var + 1e-5);
    double a = (double)gamma[co] * rstd;
    af[co] = (float)a;
    bf[co] = (float)((double)beta[co] - mean * a);
  }
}

// ---------------------------------------------------------------------------
// K5: BN affine + exact GELU + fp32 store
// ---------------------------------------------------------------------------
__global__ __launch_bounds__(256) void act_kernel(
    const float* __restrict__ outpre, const float* __restrict__ af,
    const float* __restrict__ bf, float* __restrict__ out) {
  size_t i = ((size_t)blockIdx.x * 256 + threadIdx.x) * 4;
  int co = (int)((i / N_) % COUT_);
  float a = af[co], c = bf[co];
  float4 v = *(const float4*)(outpre + i);
  float y0 = a * v.x + c, y1 = a * v.y + c, y2 = a * v.z + c, y3 = a * v.w + c;
  const float is2 = 0.70710678118654752f;
  float4 r;
  r.x = 0.5f * y0 * (1.0f + erff(y0 * is2));
  r.y = 0.5f * y1 * (1.0f + erff(y1 * is2));
  r.z = 0.5f * y2 * (1.0f + erff(y2 * is2));
  r.w = 0.5f * y3 * (1.0f + erff(y3 * is2));
  *reinterpret_cast<float4*>(out + i) = r;
}

// ---------------------------------------------------------------------------
extern "C" void kernel_launch(void* const* d_in, const int* in_sizes, int n_in,
                              void* d_out, int out_size, void* d_ws, size_t ws_size,
                              hipStream_t stream) {
  const float* x      = (const float*)d_in[0];
  const float* conv_w = (const float*)d_in[1];
  const float* conv_b = (const float*)d_in[2];
  const float* gamma  = (const float*)d_in[3];
  const float* beta   = (const float*)d_in[4];
  float* out = (float*)d_out;

  // ws layout (peak = R9's proven 78.1 MB):
  //  phase A (norm+knn): xn [0,4.82M) | xnT [4.82M,11.11M) | sqp [..11.14M)
  //  phase B (fconv+):   psum/pss/af/bf overlay dead xn @0 | outpre [9.63M,19.27M)
  //  persistent:         nn9 @19.27M
  float* buf0 = (float*)d_ws;
  float* xn   = buf0;                                    // NPTS*C
  float* xnT  = buf0 + (size_t)NPTS_ * C_;               // B*C*NP
  float* sqp  = xnT + (size_t)B_ * C_ * NP_;             // B*NP
  float* outpre = buf0 + (size_t)B_ * 2 * C_ * N_;       // [9.63M,19.27M)
  int*   nn9  = (int*)(outpre + (size_t)B_ * COUT_ * N_);// NPTS*9
  float* psum = buf0;                                    // overlay dead xn
  float* pss  = psum + COUT_ * NTILES_;
  float* af   = pss + COUT_ * NTILES_;
  float* bfv  = af + COUT_;

  const int npad_total = B_ * C_ * (NP_ - N_) + B_ * (NP_ - N_);
  hipLaunchKernelGGL(pad_kernel, dim3((npad_total + 255) / 256), dim3(256), 0, stream,
                     xnT, sqp);
  hipLaunchKernelGGL(norm_kernel, dim3((NPTS_ + 255) / 256), dim3(256), 0, stream,
                     x, xn, xnT, sqp);
  hipLaunchKernelGGL(knn_kernel, dim3(N_ / QPB_, B_), dim3(256), 0, stream,
                     xn, xnT, sqp, nn9);
  hipLaunchKernelGGL(fconv_kernel, dim3(7, 8, B_), dim3(256), 0, stream,
                     x, nn9, conv_w, conv_b, outpre, psum, pss);
  hipLaunchKernelGGL(stats_kernel, dim3(COUT_), dim3(64), 0, stream,
                     psum, pss, gamma, beta, af, bfv);
  hipLaunchKernelGGL(act_kernel, dim3((B_ * COUT_ * N_) / (256 * 4)), dim3(256), 0, stream,
                     outpre, af, bfv, out);
}

// Round 11
// 313.321 us; speedup vs baseline: 2.7372x; 1.1493x over previous
//
#include <hip/hip_runtime.h>
#include <hip/hip_bf16.h>

#define B_    32
#define C_    192
#define N_    784
#define NP_   1024        // padded candidate dim
#define K_    9
#define COUT_ 384
#define NPTS_ (B_ * N_)   // 25088
#define QPB_  16          // queries per knn block
#define NTILES_ 224       // 32 b * 7 ntiles

// ordered-uint transform: monotone map float -> uint
__device__ __forceinline__ unsigned int ford(float f) {
  unsigned int u = __float_as_uint(f);
  return u ^ ((u & 0x80000000u) ? 0xFFFFFFFFu : 0x80000000u);
}

// ---------------------------------------------------------------------------
// K0: write padding region of xnT (zeros) and sqp (+1e30) — every launch.
// ---------------------------------------------------------------------------
__global__ __launch_bounds__(256) void pad_kernel(
    float* __restrict__ xnT, float* __restrict__ sqp) {
  int i = blockIdx.x * 256 + threadIdx.x;
  const int npad = B_ * C_ * (NP_ - N_);
  if (i < npad) {
    int j  = i % (NP_ - N_);
    int cc = (i / (NP_ - N_)) % C_;
    int bb = i / ((NP_ - N_) * C_);
    xnT[((size_t)bb * C_ + cc) * NP_ + N_ + j] = 0.f;
  }
  int s = i - npad;
  if (s >= 0 && s < B_ * (NP_ - N_)) {
    int j = s % (NP_ - N_), bb = s / (NP_ - N_);
    sqp[(size_t)bb * NP_ + N_ + j] = 1e30f;
  }
}

// ---------------------------------------------------------------------------
// K1: parallel norm. Block = 64 points x 4 c-groups (256 thr).
//  ssq via per-thread partials + LDS tree (order change vs np: ~1e-7 rel,
//  rank-safe scale — same class as the proven-safe fma switch).
//  Writes only xnT (coalesced) + sqp. xn row-major buffer eliminated.
// ---------------------------------------------------------------------------
__global__ __launch_bounds__(256) void norm_kernel(
    const float* __restrict__ x, float* __restrict__ xnT,
    float* __restrict__ sqp) {
  int t = threadIdx.x;
  int pl = t & 63, cg = t >> 6;
  int p = blockIdx.x * 64 + pl;
  int b = p / N_, n = p % N_;
  const float* xb = x + (size_t)b * C_ * N_ + n;

  __shared__ float red[4][64];
  __shared__ float nrmS[64];

  float part = 0.f;
  #pragma unroll 8
  for (int j = 0; j < 48; j++) {
    float v = xb[(size_t)(cg * 48 + j) * N_];
    part = __fmaf_rn(v, v, part);
  }
  red[cg][pl] = part;
  __syncthreads();
  if (t < 64) {
    float ssq = __fadd_rn(__fadd_rn(red[0][t], red[1][t]),
                          __fadd_rn(red[2][t], red[3][t]));
    nrmS[t] = fmaxf(__fsqrt_rn(ssq), 1e-12f);
  }
  __syncthreads();
  float nrm = nrmS[pl];
  float* xt = xnT + (size_t)b * C_ * NP_ + n;
  float p2 = 0.f;
  #pragma unroll 8
  for (int j = 0; j < 48; j++) {
    float a = __fdiv_rn(xb[(size_t)(cg * 48 + j) * N_], nrm);
    xt[(size_t)(cg * 48 + j) * NP_] = a;
    p2 = __fmaf_rn(a, a, p2);
  }
  red[cg][pl] = p2;
  __syncthreads();
  if (t < 64) {
    float sq = __fadd_rn(__fadd_rn(red[0][t], red[1][t]),
                         __fadd_rn(red[2][t], red[3][t]));
    int pp = blockIdx.x * 64 + t;
    sqp[(size_t)(pp / N_) * NP_ + (pp % N_)] = sq;
  }
}

// ---------------------------------------------------------------------------
// K2: register-tiled KNN, QPB=16. Thread t owns candidates {4t..4t+3}.
//  Dot: 64 fma per c per thread, 1 dwordx4 global + 4 b128 LDS broadcast.
//  Per-candidate fma chain over c identical order to prior rounds.
//  Selection: dk holds ford keys; wave loads its query's 1024 keys into
//  16 regs once; 9 knockout rounds fully in registers + u64 lex butterfly.
// ---------------------------------------------------------------------------
__global__ __launch_bounds__(256, 4) void knn_kernel(
    const float* __restrict__ xnT, const float* __restrict__ sqp,
    int* __restrict__ nn9) {
  int qt = blockIdx.x;
  int b  = blockIdx.y;
  int t  = threadIdx.x;
  int q0 = qt * QPB_;

  __shared__ float qv[C_][QPB_];       // 12 KB (transposed query tile)
  __shared__ unsigned int dk[4][NP_];  // 16 KB (ford keys, 4 queries/pass)

  const float* bT  = xnT + (size_t)b * C_ * NP_;
  const float* sqb = sqp + (size_t)b * NP_;

  for (int i = t; i < C_ * QPB_; i += 256) {
    int c = i >> 4, qi = i & 15;
    qv[c][qi] = bT[(size_t)c * NP_ + q0 + qi];
  }
  __syncthreads();

  float acc[QPB_][4];
  #pragma unroll
  for (int qi = 0; qi < QPB_; qi++)
    #pragma unroll
    for (int j = 0; j < 4; j++) acc[qi][j] = 0.f;

  #pragma unroll 2
  for (int c = 0; c < C_; c++) {
    float4 cv = *((const float4*)(bT + (size_t)c * NP_) + t);
    float4 qa = *(const float4*)(&qv[c][0]);
    float4 qb = *(const float4*)(&qv[c][4]);
    float4 qc = *(const float4*)(&qv[c][8]);
    float4 qd = *(const float4*)(&qv[c][12]);
    float qarr[QPB_] = {qa.x, qa.y, qa.z, qa.w, qb.x, qb.y, qb.z, qb.w,
                        qc.x, qc.y, qc.z, qc.w, qd.x, qd.y, qd.z, qd.w};
    #pragma unroll
    for (int qi = 0; qi < QPB_; qi++) {
      acc[qi][0] = __fmaf_rn(qarr[qi], cv.x, acc[qi][0]);
      acc[qi][1] = __fmaf_rn(qarr[qi], cv.y, acc[qi][1]);
      acc[qi][2] = __fmaf_rn(qarr[qi], cv.z, acc[qi][2]);
      acc[qi][3] = __fmaf_rn(qarr[qi], cv.w, acc[qi][3]);
    }
  }

  float4 sv = *((const float4*)sqb + t);
  int lane = t & 63;
  int w    = t >> 6;

  for (int grp = 0; grp < 4; grp++) {
    #pragma unroll
    for (int qj = 0; qj < 4; qj++) {
      int qi = grp * 4 + qj;
      float sqq = sqb[q0 + qi];
      uint4 dv;
      dv.x = ford(__fadd_rn(__fsub_rn(sqq, __fmul_rn(2.0f, acc[qi][0])), sv.x));
      dv.y = ford(__fadd_rn(__fsub_rn(sqq, __fmul_rn(2.0f, acc[qi][1])), sv.y));
      dv.z = ford(__fadd_rn(__fsub_rn(sqq, __fmul_rn(2.0f, acc[qi][2])), sv.z));
      dv.w = ford(__fadd_rn(__fsub_rn(sqq, __fmul_rn(2.0f, acc[qi][3])), sv.w));
      *(uint4*)(&dk[qj][4 * t]) = dv;
    }
    __syncthreads();

    // wave w selects for query q0 + grp*4 + w; keys register-resident
    unsigned int kv[16];
    #pragma unroll
    for (int it = 0; it < 16; it++) kv[it] = dk[w][lane + 64 * it];
    int* o = nn9 + ((size_t)b * N_ + q0 + grp * 4 + w) * K_;
    for (int kk = 0; kk < K_; kk++) {
      unsigned int bv = 0xFFFFFFFFu; int bi = 0;
      #pragma unroll
      for (int it = 0; it < 16; it++) {
        if (kv[it] < bv) { bv = kv[it]; bi = lane + 64 * it; }  // strict < :
      }                                  // ascending idx keeps lowest idx
      unsigned long long mk = ((unsigned long long)bv << 10) | (unsigned int)bi;
      #pragma unroll
      for (int off = 1; off < 64; off <<= 1) {
        unsigned long long v2 = __shfl_xor(mk, off);
        mk = v2 < mk ? v2 : mk;
      }
      int widx = (int)(mk & 1023u);
      if (lane == 0) o[kk] = widx;
      if ((widx & 63) == lane) {        // knockout (static-index chain)
        int slot = widx >> 6;
        #pragma unroll
        for (int it = 0; it < 16; it++)
          if (it == slot) kv[it] = 0xFFFFFFFFu;
      }
    }
    __syncthreads();  // before dk reuse
  }
}

// ---------------------------------------------------------------------------
// K3: FUSED gather + max-relative + grouped 1x1 conv + BN partial sums.
// ---------------------------------------------------------------------------
__global__ __launch_bounds__(256) void fconv_kernel(
    const float* __restrict__ x, const int* __restrict__ nn9,
    const float* __restrict__ w, const float* __restrict__ bias,
    float* __restrict__ outpre, float* __restrict__ psum,
    float* __restrict__ pss) {
  int nt = blockIdx.x;
  int gh = blockIdx.y;
  int b  = blockIdx.z;
  int g = gh >> 1, half = gh & 1;
  int n0 = nt * 112;
  int t = threadIdx.x;

  __shared__ float Wl[48][97];
  __shared__ float Hl[96][112];
  __shared__ unsigned short Il[112][K_];

  const float* wsrc = w + (size_t)(g * 96 + half * 48) * 96;
  for (int i = t; i < 48 * 96; i += 256) Wl[i / 96][i % 96] = wsrc[i];
  const int* isrc = nn9 + ((size_t)b * N_ + n0) * K_;
  for (int i = t; i < 112 * K_; i += 256)
    Il[i / K_][i % K_] = (unsigned short)isrc[i];
  __syncthreads();

  const float* xb = x + (size_t)b * C_ * N_;
  for (int pos = t; pos < 48 * 112; pos += 256) {
    int cl = pos / 112, nl = pos % 112;
    const float* row = xb + (size_t)(g * 48 + cl) * N_;
    float xv = row[n0 + nl];
    float mx = -1e30f;
    #pragma unroll
    for (int k = 0; k < K_; k++) mx = fmaxf(mx, row[Il[nl][k]]);
    Hl[2 * cl][nl]     = xv;
    Hl[2 * cl + 1][nl] = mx - xv;
  }
  __syncthreads();

  int tx = t & 15, ty = t >> 4;
  float o[3][7];
  #pragma unroll
  for (int i = 0; i < 3; i++)
    #pragma unroll
    for (int j = 0; j < 7; j++) o[i][j] = 0.f;

  for (int k = 0; k < 96; k++) {
    float w0 = Wl[ty * 3 + 0][k];
    float w1 = Wl[ty * 3 + 1][k];
    float w2 = Wl[ty * 3 + 2][k];
    #pragma unroll
    for (int j = 0; j < 7; j++) {
      float hv = Hl[k][tx * 7 + j];
      o[0][j] = __fmaf_rn(w0, hv, o[0][j]);
      o[1][j] = __fmaf_rn(w1, hv, o[1][j]);
      o[2][j] = __fmaf_rn(w2, hv, o[2][j]);
    }
  }

  #pragma unroll
  for (int i = 0; i < 3; i++) {
    int co = g * 96 + half * 48 + ty * 3 + i;
    float bv = bias[co];
    float s = 0.f, s2 = 0.f;
    float* orow = outpre + ((size_t)b * COUT_ + co) * N_ + n0 + tx * 7;
    #pragma unroll
    for (int j = 0; j < 7; j++) {
      float v = o[i][j] + bv;
      orow[j] = v;
      s += v; s2 += v * v;
    }
    #pragma unroll
    for (int off = 1; off < 16; off <<= 1) {
      s  += __shfl_xor(s, off);
      s2 += __shfl_xor(s2, off);
    }
    if (tx == 0) {
      int tidx = b * 7 + nt;
      psum[co * NTILES_ + tidx] = s;
      pss [co * NTILES_ + tidx] = s2;
    }
  }
}

// ---------------------------------------------------------------------------
// K4: finalize BN stats -> per-channel affine a, b
// ---------------------------------------------------------------------------
__global__ __launch_bounds__(64) void stats_kernel(
    const float* __restrict__ psum, const float* __restrict__ pss,
    const float* __restrict__ gamma, const float* __restrict__ beta,
    float* __restrict__ af, float* __restrict__ bf) {
  int co = blockIdx.x;
  int l = threadIdx.x;
  double s = 0.0, s2 = 0.0;
  for (int i = l; i < NTILES_; i += 64) {
    s  += (double)psum[co * NTILES_ + i];
    s2 += (double)pss [co * NTILES_ + i];
  }
  #pragma unroll
  for (int o = 32; o > 0; o >>= 1) { s += __shfl_xor(s, o); s2 += __shfl_xor(s2, o); }
  if (l == 0) {
    const double cnt = (double)NPTS_;
    double mean = s / cnt;
    double var  = s2 / cnt - mean * mean;
    double rstd = 1.0 / sqrt(var + 1e-5);
    double a = (double)gamma[co] * rstd;
    af[co] = (float)a;
    bf[co] = (float)((double)beta[co] - mean * a);
  }
}

// ---------------------------------------------------------------------------
// K5: BN affine + exact GELU + fp32 store
// ---------------------------------------------------------------------------
__global__ __launch_bounds__(256) void act_kernel(
    const float* __restrict__ outpre, const float* __restrict__ af,
    const float* __restrict__ bf, float* __restrict__ out) {
  size_t i = ((size_t)blockIdx.x * 256 + threadIdx.x) * 4;
  int co = (int)((i / N_) % COUT_);
  float a = af[co], c = bf[co];
  float4 v = *(const float4*)(outpre + i);
  float y0 = a * v.x + c, y1 = a * v.y + c, y2 = a * v.z + c, y3 = a * v.w + c;
  const float is2 = 0.70710678118654752f;
  float4 r;
  r.x = 0.5f * y0 * (1.0f + erff(y0 * is2));
  r.y = 0.5f * y1 * (1.0f + erff(y1 * is2));
  r.z = 0.5f * y2 * (1.0f + erff(y2 * is2));
  r.w = 0.5f * y3 * (1.0f + erff(y3 * is2));
  *reinterpret_cast<float4*>(out + i) = r;
}

// ---------------------------------------------------------------------------
extern "C" void kernel_launch(void* const* d_in, const int* in_sizes, int n_in,
                              void* d_out, int out_size, void* d_ws, size_t ws_size,
                              hipStream_t stream) {
  const float* x      = (const float*)d_in[0];
  const float* conv_w = (const float*)d_in[1];
  const float* conv_b = (const float*)d_in[2];
  const float* gamma  = (const float*)d_in[3];
  const float* beta   = (const float*)d_in[4];
  float* out = (float*)d_out;

  // ws layout, fully disjoint (~65.6 MB < proven 78 MB):
  float* buf0 = (float*)d_ws;
  float* xnT  = buf0;                                   // B*C*NP = 6,291,456
  float* sqp  = xnT + (size_t)B_ * C_ * NP_;            // B*NP   = 32,768
  int*   nn9  = (int*)(sqp + (size_t)B_ * NP_);         // NPTS*9 = 225,792
  float* outpre = (float*)(nn9 + (size_t)NPTS_ * K_);   // B*COUT*N = 9,633,792
  float* psum = outpre + (size_t)B_ * COUT_ * N_;       // 384*224
  float* pss  = psum + COUT_ * NTILES_;
  float* af   = pss + COUT_ * NTILES_;
  float* bfv  = af + COUT_;

  const int npad_total = B_ * C_ * (NP_ - N_) + B_ * (NP_ - N_);
  hipLaunchKernelGGL(pad_kernel, dim3((npad_total + 255) / 256), dim3(256), 0, stream,
                     xnT, sqp);
  hipLaunchKernelGGL(norm_kernel, dim3(NPTS_ / 64), dim3(256), 0, stream,
                     x, xnT, sqp);
  hipLaunchKernelGGL(knn_kernel, dim3(N_ / QPB_, B_), dim3(256), 0, stream,
                     xnT, sqp, nn9);
  hipLaunchKernelGGL(fconv_kernel, dim3(7, 8, B_), dim3(256), 0, stream,
                     x, nn9, conv_w, conv_b, outpre, psum, pss);
  hipLaunchKernelGGL(stats_kernel, dim3(COUT_), dim3(64), 0, stream,
                     psum, pss, gamma, beta, af, bfv);
  hipLaunchKernelGGL(act_kernel, dim3((B_ * COUT_ * N_) / (256 * 4)), dim3(256), 0, stream,
                     outpre, af, bfv, out);
}

// Round 12
// 308.140 us; speedup vs baseline: 2.7833x; 1.0168x over previous
//
#include <hip/hip_runtime.h>
#include <hip/hip_bf16.h>

#define B_    32
#define C_    192
#define N_    784
#define NP_   1024        // padded candidate dim
#define K_    9
#define COUT_ 384
#define NPTS_ (B_ * N_)   // 25088
#define QPB_  16          // queries per knn block
#define NTILES_ 224       // 32 b * 7 ntiles

// ordered-uint transform: monotone map float -> uint
__device__ __forceinline__ unsigned int ford(float f) {
  unsigned int u = __float_as_uint(f);
  return u ^ ((u & 0x80000000u) ? 0xFFFFFFFFu : 0x80000000u);
}

// ---------------------------------------------------------------------------
// K0: write padding region of xnT (zeros) and sqp (+1e30) — every launch.
// ---------------------------------------------------------------------------
__global__ __launch_bounds__(256) void pad_kernel(
    float* __restrict__ xnT, float* __restrict__ sqp) {
  int i = blockIdx.x * 256 + threadIdx.x;
  const int npad = B_ * C_ * (NP_ - N_);
  if (i < npad) {
    int j  = i % (NP_ - N_);
    int cc = (i / (NP_ - N_)) % C_;
    int bb = i / ((NP_ - N_) * C_);
    xnT[((size_t)bb * C_ + cc) * NP_ + N_ + j] = 0.f;
  }
  int s = i - npad;
  if (s >= 0 && s < B_ * (NP_ - N_)) {
    int j = s % (NP_ - N_), bb = s / (NP_ - N_);
    sqp[(size_t)bb * NP_ + N_ + j] = 1e30f;
  }
}

// ---------------------------------------------------------------------------
// K1: parallel norm. Block = 64 points x 4 c-groups (256 thr).
// ---------------------------------------------------------------------------
__global__ __launch_bounds__(256) void norm_kernel(
    const float* __restrict__ x, float* __restrict__ xnT,
    float* __restrict__ sqp) {
  int t = threadIdx.x;
  int pl = t & 63, cg = t >> 6;
  int p = blockIdx.x * 64 + pl;
  int b = p / N_, n = p % N_;
  const float* xb = x + (size_t)b * C_ * N_ + n;

  __shared__ float red[4][64];
  __shared__ float nrmS[64];

  float part = 0.f;
  #pragma unroll 8
  for (int j = 0; j < 48; j++) {
    float v = xb[(size_t)(cg * 48 + j) * N_];
    part = __fmaf_rn(v, v, part);
  }
  red[cg][pl] = part;
  __syncthreads();
  if (t < 64) {
    float ssq = __fadd_rn(__fadd_rn(red[0][t], red[1][t]),
                          __fadd_rn(red[2][t], red[3][t]));
    nrmS[t] = fmaxf(__fsqrt_rn(ssq), 1e-12f);
  }
  __syncthreads();
  float nrm = nrmS[pl];
  float* xt = xnT + (size_t)b * C_ * NP_ + n;
  float p2 = 0.f;
  #pragma unroll 8
  for (int j = 0; j < 48; j++) {
    float a = __fdiv_rn(xb[(size_t)(cg * 48 + j) * N_], nrm);
    xt[(size_t)(cg * 48 + j) * NP_] = a;
    p2 = __fmaf_rn(a, a, p2);
  }
  red[cg][pl] = p2;
  __syncthreads();
  if (t < 64) {
    float sq = __fadd_rn(__fadd_rn(red[0][t], red[1][t]),
                         __fadd_rn(red[2][t], red[3][t]));
    int pp = blockIdx.x * 64 + t;
    sqp[(size_t)(pp / N_) * NP_ + (pp % N_)] = sq;
  }
}

// ---------------------------------------------------------------------------
// K2: register-tiled KNN, QPB=16, no VGPR cap (launch_bounds 256 only).
//  Dot: thread t owns candidates {4t..4t+3}; 64 fma : 1 dwordx4 : 4 b128.
//  Selection: per-lane running (bv,bi) over its 16-key LDS strip; butterfly
//  lane-mins; winner's owner lane knocks out in LDS + rescans its strip.
// ---------------------------------------------------------------------------
__global__ __launch_bounds__(256) void knn_kernel(
    const float* __restrict__ xnT, const float* __restrict__ sqp,
    int* __restrict__ nn9) {
  int qt = blockIdx.x;
  int b  = blockIdx.y;
  int t  = threadIdx.x;
  int q0 = qt * QPB_;

  __shared__ float qv[C_][QPB_];       // 12 KB (transposed query tile)
  __shared__ unsigned int dk[4][NP_];  // 16 KB (ford keys, 4 queries/pass)

  const float* bT  = xnT + (size_t)b * C_ * NP_;
  const float* sqb = sqp + (size_t)b * NP_;

  for (int i = t; i < C_ * QPB_; i += 256) {
    int c = i >> 4, qi = i & 15;
    qv[c][qi] = bT[(size_t)c * NP_ + q0 + qi];
  }
  __syncthreads();

  float acc[QPB_][4];
  #pragma unroll
  for (int qi = 0; qi < QPB_; qi++)
    #pragma unroll
    for (int j = 0; j < 4; j++) acc[qi][j] = 0.f;

  #pragma unroll 2
  for (int c = 0; c < C_; c++) {
    float4 cv = *((const float4*)(bT + (size_t)c * NP_) + t);
    float4 qa = *(const float4*)(&qv[c][0]);
    float4 qb = *(const float4*)(&qv[c][4]);
    float4 qc = *(const float4*)(&qv[c][8]);
    float4 qd = *(const float4*)(&qv[c][12]);
    float qarr[QPB_] = {qa.x, qa.y, qa.z, qa.w, qb.x, qb.y, qb.z, qb.w,
                        qc.x, qc.y, qc.z, qc.w, qd.x, qd.y, qd.z, qd.w};
    #pragma unroll
    for (int qi = 0; qi < QPB_; qi++) {
      acc[qi][0] = __fmaf_rn(qarr[qi], cv.x, acc[qi][0]);
      acc[qi][1] = __fmaf_rn(qarr[qi], cv.y, acc[qi][1]);
      acc[qi][2] = __fmaf_rn(qarr[qi], cv.z, acc[qi][2]);
      acc[qi][3] = __fmaf_rn(qarr[qi], cv.w, acc[qi][3]);
    }
  }

  float4 sv = *((const float4*)sqb + t);
  int lane = t & 63;
  int w    = t >> 6;

  for (int grp = 0; grp < 4; grp++) {
    #pragma unroll
    for (int qj = 0; qj < 4; qj++) {
      int qi = grp * 4 + qj;
      float sqq = sqb[q0 + qi];
      uint4 dv;
      dv.x = ford(__fadd_rn(__fsub_rn(sqq, __fmul_rn(2.0f, acc[qi][0])), sv.x));
      dv.y = ford(__fadd_rn(__fsub_rn(sqq, __fmul_rn(2.0f, acc[qi][1])), sv.y));
      dv.z = ford(__fadd_rn(__fsub_rn(sqq, __fmul_rn(2.0f, acc[qi][2])), sv.z));
      dv.w = ford(__fadd_rn(__fsub_rn(sqq, __fmul_rn(2.0f, acc[qi][3])), sv.w));
      *(uint4*)(&dk[qj][4 * t]) = dv;
    }
    __syncthreads();

    // wave w selects for query q0 + grp*4 + w
    unsigned int bv = 0xFFFFFFFFu; int bi = lane;
    #pragma unroll
    for (int it = 0; it < 16; it++) {
      unsigned int k = dk[w][lane + 64 * it];
      if (k < bv) { bv = k; bi = lane + 64 * it; }
    }
    int* o = nn9 + ((size_t)b * N_ + q0 + grp * 4 + w) * K_;
    for (int kk = 0; kk < K_; kk++) {
      unsigned long long mk = ((unsigned long long)bv << 10) | (unsigned int)bi;
      #pragma unroll
      for (int off = 1; off < 64; off <<= 1) {
        unsigned long long v2 = __shfl_xor(mk, off);
        mk = v2 < mk ? v2 : mk;
      }
      int widx = (int)(mk & 1023u);
      if (lane == 0) o[kk] = widx;
      if ((widx & 63) == lane) {    // owner lane: knockout + rescan strip
        dk[w][widx] = 0xFFFFFFFFu;
        bv = 0xFFFFFFFFu; bi = lane;
        #pragma unroll
        for (int it = 0; it < 16; it++) {
          unsigned int k = dk[w][lane + 64 * it];
          if (k < bv) { bv = k; bi = lane + 64 * it; }
        }
      }
    }
    __syncthreads();  // before dk reuse
  }
}

// ---------------------------------------------------------------------------
// K3: FUSED gather + max-relative + grouped 1x1 conv + BN partial sums.
// ---------------------------------------------------------------------------
__global__ __launch_bounds__(256) void fconv_kernel(
    const float* __restrict__ x, const int* __restrict__ nn9,
    const float* __restrict__ w, const float* __restrict__ bias,
    float* __restrict__ outpre, float* __restrict__ psum,
    float* __restrict__ pss) {
  int nt = blockIdx.x;
  int gh = blockIdx.y;
  int b  = blockIdx.z;
  int g = gh >> 1, half = gh & 1;
  int n0 = nt * 112;
  int t = threadIdx.x;

  __shared__ float Wl[48][97];
  __shared__ float Hl[96][112];
  __shared__ unsigned short Il[112][K_];

  const float* wsrc = w + (size_t)(g * 96 + half * 48) * 96;
  for (int i = t; i < 48 * 96; i += 256) Wl[i / 96][i % 96] = wsrc[i];
  const int* isrc = nn9 + ((size_t)b * N_ + n0) * K_;
  for (int i = t; i < 112 * K_; i += 256)
    Il[i / K_][i % K_] = (unsigned short)isrc[i];
  __syncthreads();

  const float* xb = x + (size_t)b * C_ * N_;
  for (int pos = t; pos < 48 * 112; pos += 256) {
    int cl = pos / 112, nl = pos % 112;
    const float* row = xb + (size_t)(g * 48 + cl) * N_;
    float xv = row[n0 + nl];
    float mx = -1e30f;
    #pragma unroll
    for (int k = 0; k < K_; k++) mx = fmaxf(mx, row[Il[nl][k]]);
    Hl[2 * cl][nl]     = xv;
    Hl[2 * cl + 1][nl] = mx - xv;
  }
  __syncthreads();

  int tx = t & 15, ty = t >> 4;
  float o[3][7];
  #pragma unroll
  for (int i = 0; i < 3; i++)
    #pragma unroll
    for (int j = 0; j < 7; j++) o[i][j] = 0.f;

  for (int k = 0; k < 96; k++) {
    float w0 = Wl[ty * 3 + 0][k];
    float w1 = Wl[ty * 3 + 1][k];
    float w2 = Wl[ty * 3 + 2][k];
    #pragma unroll
    for (int j = 0; j < 7; j++) {
      float hv = Hl[k][tx * 7 + j];
      o[0][j] = __fmaf_rn(w0, hv, o[0][j]);
      o[1][j] = __fmaf_rn(w1, hv, o[1][j]);
      o[2][j] = __fmaf_rn(w2, hv, o[2][j]);
    }
  }

  #pragma unroll
  for (int i = 0; i < 3; i++) {
    int co = g * 96 + half * 48 + ty * 3 + i;
    float bv = bias[co];
    float s = 0.f, s2 = 0.f;
    float* orow = outpre + ((size_t)b * COUT_ + co) * N_ + n0 + tx * 7;
    #pragma unroll
    for (int j = 0; j < 7; j++) {
      float v = o[i][j] + bv;
      orow[j] = v;
      s += v; s2 += v * v;
    }
    #pragma unroll
    for (int off = 1; off < 16; off <<= 1) {
      s  += __shfl_xor(s, off);
      s2 += __shfl_xor(s2, off);
    }
    if (tx == 0) {
      int tidx = b * 7 + nt;
      psum[co * NTILES_ + tidx] = s;
      pss [co * NTILES_ + tidx] = s2;
    }
  }
}

// ---------------------------------------------------------------------------
// K4: finalize BN stats -> per-channel affine a, b
// ---------------------------------------------------------------------------
__global__ __launch_bounds__(64) void stats_kernel(
    const float* __restrict__ psum, const float* __restrict__ pss,
    const float* __restrict__ gamma, const float* __restrict__ beta,
    float* __restrict__ af, float* __restrict__ bf) {
  int co = blockIdx.x;
  int l = threadIdx.x;
  double s = 0.0, s2 = 0.0;
  for (int i = l; i < NTILES_; i += 64) {
    s  += (double)psum[co * NTILES_ + i];
    s2 += (double)pss [co * NTILES_ + i];
  }
  #pragma unroll
  for (int o = 32; o > 0; o >>= 1) { s += __shfl_xor(s, o); s2 += __shfl_xor(s2, o); }
  if (l == 0) {
    const double cnt = (double)NPTS_;
    double mean = s / cnt;
    double var  = s2 / cnt - mean * mean;
    double rstd = 1.0 / sqrt(var + 1e-5);
    double a = (double)gamma[co] * rstd;
    af[co] = (float)a;
    bf[co] = (float)((double)beta[co] - mean * a);
  }
}

// ---------------------------------------------------------------------------
// K5: BN affine + exact GELU + fp32 store
// ---------------------------------------------------------------------------
__global__ __launch_bounds__(256) void act_kernel(
    const float* __restrict__ outpre, const float* __restrict__ af,
    const float* __restrict__ bf, float* __restrict__ out) {
  size_t i = ((size_t)blockIdx.x * 256 + threadIdx.x) * 4;
  int co = (int)((i / N_) % COUT_);
  float a = af[co], c = bf[co];
  float4 v = *(const float4*)(outpre + i);
  float y0 = a * v.x + c, y1 = a * v.y + c, y2 = a * v.z + c, y3 = a * v.w + c;
  const float is2 = 0.70710678118654752f;
  float4 r;
  r.x = 0.5f * y0 * (1.0f + erff(y0 * is2));
  r.y = 0.5f * y1 * (1.0f + erff(y1 * is2));
  r.z = 0.5f * y2 * (1.0f + erff(y2 * is2));
  r.w = 0.5f * y3 * (1.0f + erff(y3 * is2));
  *reinterpret_cast<float4*>(out + i) = r;
}

// ---------------------------------------------------------------------------
extern "C" void kernel_launch(void* const* d_in, const int* in_sizes, int n_in,
                              void* d_out, int out_size, void* d_ws, size_t ws_size,
                              hipStream_t stream) {
  const float* x      = (const float*)d_in[0];
  const float* conv_w = (const float*)d_in[1];
  const float* conv_b = (const float*)d_in[2];
  const float* gamma  = (const float*)d_in[3];
  const float* beta   = (const float*)d_in[4];
  float* out = (float*)d_out;

  float* buf0 = (float*)d_ws;
  float* xnT  = buf0;                                   // B*C*NP
  float* sqp  = xnT + (size_t)B_ * C_ * NP_;            // B*NP
  int*   nn9  = (int*)(sqp + (size_t)B_ * NP_);         // NPTS*9
  float* outpre = (float*)(nn9 + (size_t)NPTS_ * K_);   // B*COUT*N
  float* psum = outpre + (size_t)B_ * COUT_ * N_;       // 384*224
  float* pss  = psum + COUT_ * NTILES_;
  float* af   = pss + COUT_ * NTILES_;
  float* bfv  = af + COUT_;

  const int npad_total = B_ * C_ * (NP_ - N_) + B_ * (NP_ - N_);
  hipLaunchKernelGGL(pad_kernel, dim3((npad_total + 255) / 256), dim3(256), 0, stream,
                     xnT, sqp);
  hipLaunchKernelGGL(norm_kernel, dim3(NPTS_ / 64), dim3(256), 0, stream,
                     x, xnT, sqp);
  hipLaunchKernelGGL(knn_kernel, dim3(N_ / QPB_, B_), dim3(256), 0, stream,
                     xnT, sqp, nn9);
  hipLaunchKernelGGL(fconv_kernel, dim3(7, 8, B_), dim3(256), 0, stream,
                     x, nn9, conv_w, conv_b, outpre, psum, pss);
  hipLaunchKernelGGL(stats_kernel, dim3(COUT_), dim3(64), 0, stream,
                     psum, pss, gamma, beta, af, bfv);
  hipLaunchKernelGGL(act_kernel, dim3((B_ * COUT_ * N_) / (256 * 4)), dim3(256), 0, stream,
                     outpre, af, bfv, out);
}

// Round 13
// 265.681 us; speedup vs baseline: 3.2281x; 1.1598x over previous
//
#include <hip/hip_runtime.h>

#define B_    32
#define C_    192
#define N_    784
#define NP_   1024        // padded candidate dim
#define K_    9
#define COUT_ 384
#define NPTS_ (B_ * N_)   // 25088
#define QPB_  16          // queries per knn block
#define NTILES_ 224       // 32 b * 7 ntiles

typedef __attribute__((ext_vector_type(8))) short short8;   // 8 bf16 = 4 VGPR
typedef __attribute__((ext_vector_type(4))) float f32x4;    // MFMA acc

// ordered-uint transform: monotone map float -> uint
__device__ __forceinline__ unsigned int ford(float f) {
  unsigned int u = __float_as_uint(f);
  return u ^ ((u & 0x80000000u) ? 0xFFFFFFFFu : 0x80000000u);
}
// fp32 -> bf16 (RNE) without library types
__device__ __forceinline__ unsigned short f2bf(float f) {
  unsigned int u = __float_as_uint(f);
  u += 0x7FFFu + ((u >> 16) & 1u);
  return (unsigned short)(u >> 16);
}
__device__ __forceinline__ float bf2f(unsigned short h) {
  return __uint_as_float(((unsigned int)h) << 16);
}

// ---------------------------------------------------------------------------
// K0: zero xnT pad cols, set sqp pad to +1e30 — every launch.
// ---------------------------------------------------------------------------
__global__ __launch_bounds__(256) void pad_kernel(
    float* __restrict__ xnT, float* __restrict__ sqp) {
  int i = blockIdx.x * 256 + threadIdx.x;
  const int npad = B_ * C_ * (NP_ - N_);
  if (i < npad) {
    int j  = i % (NP_ - N_);
    int cc = (i / (NP_ - N_)) % C_;
    int bb = i / ((NP_ - N_) * C_);
    xnT[((size_t)bb * C_ + cc) * NP_ + N_ + j] = 0.f;
  }
  int s = i - npad;
  if (s >= 0 && s < B_ * (NP_ - N_)) {
    int j = s % (NP_ - N_), bb = s / (NP_ - N_);
    sqp[(size_t)bb * NP_ + N_ + j] = 1e30f;
  }
}

// ---------------------------------------------------------------------------
// K1: parallel norm. Block = 64 points x 4 c-groups. Writes xnT fp32 + sqp.
// ---------------------------------------------------------------------------
__global__ __launch_bounds__(256) void norm_kernel(
    const float* __restrict__ x, float* __restrict__ xnT,
    float* __restrict__ sqp) {
  int t = threadIdx.x;
  int pl = t & 63, cg = t >> 6;
  int p = blockIdx.x * 64 + pl;
  int b = p / N_, n = p % N_;
  const float* xb = x + (size_t)b * C_ * N_ + n;

  __shared__ float red[4][64];
  __shared__ float nrmS[64];

  float part = 0.f;
  #pragma unroll 8
  for (int j = 0; j < 48; j++) {
    float v = xb[(size_t)(cg * 48 + j) * N_];
    part = __fmaf_rn(v, v, part);
  }
  red[cg][pl] = part;
  __syncthreads();
  if (t < 64) {
    float ssq = __fadd_rn(__fadd_rn(red[0][t], red[1][t]),
                          __fadd_rn(red[2][t], red[3][t]));
    nrmS[t] = fmaxf(__fsqrt_rn(ssq), 1e-12f);
  }
  __syncthreads();
  float nrm = nrmS[pl];
  float* xt = xnT + (size_t)b * C_ * NP_ + n;
  float p2 = 0.f;
  #pragma unroll 8
  for (int j = 0; j < 48; j++) {
    float a = __fdiv_rn(xb[(size_t)(cg * 48 + j) * N_], nrm);
    xt[(size_t)(cg * 48 + j) * NP_] = a;
    p2 = __fmaf_rn(a, a, p2);
  }
  red[cg][pl] = p2;
  __syncthreads();
  if (t < 64) {
    float sq = __fadd_rn(__fadd_rn(red[0][t], red[1][t]),
                         __fadd_rn(red[2][t], red[3][t]));
    int pp = blockIdx.x * 64 + t;
    sqp[(size_t)(pp / N_) * NP_ + (pp % N_)] = sq;
  }
}

// ---------------------------------------------------------------------------
// K2: pack xnT (fp32, [b][c][NP]) into MFMA fragment buffers, split bf16:
//  hi = bf16(v), lo = bf16(v - hi).  Frag layout (per b, kstep, grp16):
//  lane l holds 8 bf16: element [k = ks*32 + (l>>4)*8 + j][m = grp*16 + (l&15)]
//  -> knn reads one dwordx4 per fragment. grid (mc=8, ks=6, b=32), 256 thr.
// ---------------------------------------------------------------------------
__global__ __launch_bounds__(256) void pack_kernel(
    const float* __restrict__ xnT, short8* __restrict__ fragH,
    short8* __restrict__ fragL) {
  int mc = blockIdx.x, ks = blockIdx.y, b = blockIdx.z;
  int t = threadIdx.x;
  __shared__ float T[32][133];

  const float* src = xnT + (size_t)b * C_ * NP_ + (size_t)(ks * 32) * NP_
                     + mc * 128;
  for (int i = t; i < 32 * 128; i += 256)
    T[i >> 7][i & 127] = src[(size_t)(i >> 7) * NP_ + (i & 127)];
  __syncthreads();

  for (int e = t; e < 512; e += 256) {
    int g = e >> 6, l = e & 63;
    int colL = l & 15, kq = l >> 4;
    union { short8 v; unsigned short u[8]; } ph, pl2;
    #pragma unroll
    for (int j = 0; j < 8; j++) {
      float v = T[kq * 8 + j][g * 16 + colL];
      unsigned short h = f2bf(v);
      ph.u[j]  = h;
      pl2.u[j] = f2bf(__fsub_rn(v, bf2f(h)));
    }
    size_t idx = (((size_t)b * 6 + ks) * 64 + (mc * 8 + g)) * 64 + l;
    fragH[idx] = ph.v;
    fragL[idx] = pl2.v;
  }
}

// ---------------------------------------------------------------------------
// K3: MFMA KNN. Block = 16 queries x 1024 candidates, 4 waves.
//  G = xh*xh^T + xh*xl^T + xl*xh^T via mfma_f32_16x16x32_bf16 (3 indep accs).
//  dist = (sq_q - 2G) + sq_c -> ford keys in LDS -> R12 strip-scan top-9.
//  Bijective XCD swizzle: 1568 wgs = 8 xcd x (4 b x 49 qt).
// ---------------------------------------------------------------------------
__global__ __launch_bounds__(256) void knn_kernel(
    const short8* __restrict__ fragH, const short8* __restrict__ fragL,
    const float* __restrict__ sqp, int* __restrict__ nn9) {
  int wg = blockIdx.x;
  int r = wg & 7, j = wg >> 3;
  int b  = r + 8 * (j / 49);
  int qt = j % 49;
  int q0 = qt * 16;
  int t = threadIdx.x, lane = t & 63, w = t >> 6;

  __shared__ unsigned int dkS[16][1028];  // 65.8 KB keys
  __shared__ float csqS[NP_];             // 4 KB
  __shared__ float qsqS[16];

  const float* sqb = sqp + (size_t)b * NP_;
  for (int i = t; i < NP_; i += 256) csqS[i] = sqb[i];
  if (t < 16) qsqS[t] = sqb[q0 + t];
  __syncthreads();

  const short8* fH = fragH + (size_t)b * 6 * 64 * 64;
  const short8* fL = fragL + (size_t)b * 6 * 64 * 64;

  // A-fragments: query group qt (rows q0..q0+15), all 6 K-steps, hi+lo
  short8 aH[6], aL[6];
  #pragma unroll
  for (int ks = 0; ks < 6; ks++) {
    aH[ks] = fH[((size_t)ks * 64 + qt) * 64 + lane];
    aL[ks] = fL[((size_t)ks * 64 + qt) * 64 + lane];
  }

  int colL = lane & 15, rq = lane >> 4;

  // wave w covers candidate cols [w*256, w*256+256): grps 16w..16w+15, x2
  for (int gp = 0; gp < 16; gp += 2) {
    int g0 = w * 16 + gp, g1 = g0 + 1;
    f32x4 a00 = {0.f, 0.f, 0.f, 0.f}, a01 = a00, a02 = a00;
    f32x4 a10 = a00, a11 = a00, a12 = a00;
    #pragma unroll
    for (int ks = 0; ks < 6; ks++) {
      short8 b0h = fH[((size_t)ks * 64 + g0) * 64 + lane];
      short8 b0l = fL[((size_t)ks * 64 + g0) * 64 + lane];
      short8 b1h = fH[((size_t)ks * 64 + g1) * 64 + lane];
      short8 b1l = fL[((size_t)ks * 64 + g1) * 64 + lane];
      a00 = __builtin_amdgcn_mfma_f32_16x16x32_bf16(aH[ks], b0h, a00, 0, 0, 0);
      a01 = __builtin_amdgcn_mfma_f32_16x16x32_bf16(aH[ks], b0l, a01, 0, 0, 0);
      a02 = __builtin_amdgcn_mfma_f32_16x16x32_bf16(aL[ks], b0h, a02, 0, 0, 0);
      a10 = __builtin_amdgcn_mfma_f32_16x16x32_bf16(aH[ks], b1h, a10, 0, 0, 0);
      a11 = __builtin_amdgcn_mfma_f32_16x16x32_bf16(aH[ks], b1l, a11, 0, 0, 0);
      a12 = __builtin_amdgcn_mfma_f32_16x16x32_bf16(aL[ks], b1h, a12, 0, 0, 0);
    }
    float cs0 = csqS[g0 * 16 + colL];
    float cs1 = csqS[g1 * 16 + colL];
    #pragma unroll
    for (int rr = 0; rr < 4; rr++) {
      int row = rq * 4 + rr;             // verified C/D: row=(lane>>4)*4+reg
      float qs = qsqS[row];
      float g0v = __fadd_rn(__fadd_rn(a00[rr], a01[rr]), a02[rr]);
      float g1v = __fadd_rn(__fadd_rn(a10[rr], a11[rr]), a12[rr]);
      float d0 = __fadd_rn(__fsub_rn(qs, __fmul_rn(2.0f, g0v)), cs0);
      float d1 = __fadd_rn(__fsub_rn(qs, __fmul_rn(2.0f, g1v)), cs1);
      dkS[row][g0 * 16 + colL] = ford(d0);
      dkS[row][g1 * 16 + colL] = ford(d1);
    }
  }
  __syncthreads();

  // selection: wave w handles query rows w*4 .. w*4+3 (R12 machinery)
  for (int s = 0; s < 4; s++) {
    int row = w * 4 + s;
    unsigned int bv = 0xFFFFFFFFu; int bi = lane;
    #pragma unroll
    for (int it = 0; it < 16; it++) {
      unsigned int k = dkS[row][lane + 64 * it];
      if (k < bv) { bv = k; bi = lane + 64 * it; }
    }
    int* o = nn9 + ((size_t)b * N_ + q0 + row) * K_;
    for (int kk = 0; kk < K_; kk++) {
      unsigned long long mk = ((unsigned long long)bv << 10) | (unsigned int)bi;
      #pragma unroll
      for (int off = 1; off < 64; off <<= 1) {
        unsigned long long v2 = __shfl_xor(mk, off);
        mk = v2 < mk ? v2 : mk;
      }
      int widx = (int)(mk & 1023u);
      if (lane == 0) o[kk] = widx;
      if ((widx & 63) == lane) {    // owner lane: knockout + rescan strip
        dkS[row][widx] = 0xFFFFFFFFu;
        bv = 0xFFFFFFFFu; bi = lane;
        #pragma unroll
        for (int it = 0; it < 16; it++) {
          unsigned int k = dkS[row][lane + 64 * it];
          if (k < bv) { bv = k; bi = lane + 64 * it; }
        }
      }
    }
  }
}

// ---------------------------------------------------------------------------
// K4: FUSED gather + max-relative + grouped 1x1 conv + BN partial sums.
// ---------------------------------------------------------------------------
__global__ __launch_bounds__(256) void fconv_kernel(
    const float* __restrict__ x, const int* __restrict__ nn9,
    const float* __restrict__ w, const float* __restrict__ bias,
    float* __restrict__ outpre, float* __restrict__ psum,
    float* __restrict__ pss) {
  int nt = blockIdx.x;
  int gh = blockIdx.y;
  int b  = blockIdx.z;
  int g = gh >> 1, half = gh & 1;
  int n0 = nt * 112;
  int t = threadIdx.x;

  __shared__ float Wl[48][97];
  __shared__ float Hl[96][112];
  __shared__ unsigned short Il[112][K_];

  const float* wsrc = w + (size_t)(g * 96 + half * 48) * 96;
  for (int i = t; i < 48 * 96; i += 256) Wl[i / 96][i % 96] = wsrc[i];
  const int* isrc = nn9 + ((size_t)b * N_ + n0) * K_;
  for (int i = t; i < 112 * K_; i += 256)
    Il[i / K_][i % K_] = (unsigned short)isrc[i];
  __syncthreads();

  const float* xb = x + (size_t)b * C_ * N_;
  for (int pos = t; pos < 48 * 112; pos += 256) {
    int cl = pos / 112, nl = pos % 112;
    const float* row = xb + (size_t)(g * 48 + cl) * N_;
    float xv = row[n0 + nl];
    float mx = -1e30f;
    #pragma unroll
    for (int k = 0; k < K_; k++) mx = fmaxf(mx, row[Il[nl][k]]);
    Hl[2 * cl][nl]     = xv;
    Hl[2 * cl + 1][nl] = mx - xv;
  }
  __syncthreads();

  int tx = t & 15, ty = t >> 4;
  float o[3][7];
  #pragma unroll
  for (int i = 0; i < 3; i++)
    #pragma unroll
    for (int j = 0; j < 7; j++) o[i][j] = 0.f;

  for (int k = 0; k < 96; k++) {
    float w0 = Wl[ty * 3 + 0][k];
    float w1 = Wl[ty * 3 + 1][k];
    float w2 = Wl[ty * 3 + 2][k];
    #pragma unroll
    for (int j = 0; j < 7; j++) {
      float hv = Hl[k][tx * 7 + j];
      o[0][j] = __fmaf_rn(w0, hv, o[0][j]);
      o[1][j] = __fmaf_rn(w1, hv, o[1][j]);
      o[2][j] = __fmaf_rn(w2, hv, o[2][j]);
    }
  }

  #pragma unroll
  for (int i = 0; i < 3; i++) {
    int co = g * 96 + half * 48 + ty * 3 + i;
    float bv = bias[co];
    float s = 0.f, s2 = 0.f;
    float* orow = outpre + ((size_t)b * COUT_ + co) * N_ + n0 + tx * 7;
    #pragma unroll
    for (int j = 0; j < 7; j++) {
      float v = o[i][j] + bv;
      orow[j] = v;
      s += v; s2 += v * v;
    }
    #pragma unroll
    for (int off = 1; off < 16; off <<= 1) {
      s  += __shfl_xor(s, off);
      s2 += __shfl_xor(s2, off);
    }
    if (tx == 0) {
      int tidx = b * 7 + nt;
      psum[co * NTILES_ + tidx] = s;
      pss [co * NTILES_ + tidx] = s2;
    }
  }
}

// ---------------------------------------------------------------------------
// K5: finalize BN stats -> per-channel affine a, b
// ---------------------------------------------------------------------------
__global__ __launch_bounds__(64) void stats_kernel(
    const float* __restrict__ psum, const float* __restrict__ pss,
    const float* __restrict__ gamma, const float* __restrict__ beta,
    float* __restrict__ af, float* __restrict__ bf) {
  int co = blockIdx.x;
  int l = threadIdx.x;
  double s = 0.0, s2 = 0.0;
  for (int i = l; i < NTILES_; i += 64) {
    s  += (double)psum[co * NTILES_ + i];
    s2 += (double)pss [co * NTILES_ + i];
  }
  #pragma unroll
  for (int o = 32; o > 0; o >>= 1) { s += __shfl_xor(s, o); s2 += __shfl_xor(s2, o); }
  if (l == 0) {
    const double cnt = (double)NPTS_;
    double mean = s / cnt;
    double var  = s2 / cnt - mean * mean;
    double rstd = 1.0 / sqrt(var + 1e-5);
    double a = (double)gamma[co] * rstd;
    af[co] = (float)a;
    bf[co] = (float)((double)beta[co] - mean * a);
  }
}

// ---------------------------------------------------------------------------
// K6: BN affine + exact GELU + fp32 store
// ---------------------------------------------------------------------------
__global__ __launch_bounds__(256) void act_kernel(
    const float* __restrict__ outpre, const float* __restrict__ af,
    const float* __restrict__ bf, float* __restrict__ out) {
  size_t i = ((size_t)blockIdx.x * 256 + threadIdx.x) * 4;
  int co = (int)((i / N_) % COUT_);
  float a = af[co], c = bf[co];
  float4 v = *(const float4*)(outpre + i);
  float y0 = a * v.x + c, y1 = a * v.y + c, y2 = a * v.z + c, y3 = a * v.w + c;
  const float is2 = 0.70710678118654752f;
  float4 r;
  r.x = 0.5f * y0 * (1.0f + erff(y0 * is2));
  r.y = 0.5f * y1 * (1.0f + erff(y1 * is2));
  r.z = 0.5f * y2 * (1.0f + erff(y2 * is2));
  r.w = 0.5f * y3 * (1.0f + erff(y3 * is2));
  *reinterpret_cast<float4*>(out + i) = r;
}

// ---------------------------------------------------------------------------
extern "C" void kernel_launch(void* const* d_in, const int* in_sizes, int n_in,
                              void* d_out, int out_size, void* d_ws, size_t ws_size,
                              hipStream_t stream) {
  const float* x      = (const float*)d_in[0];
  const float* conv_w = (const float*)d_in[1];
  const float* conv_b = (const float*)d_in[2];
  const float* gamma  = (const float*)d_in[3];
  const float* beta   = (const float*)d_in[4];
  float* out = (float*)d_out;

  // ws layout (floats), peak 52.1 MB:
  //  [0, 6291456)            xnT fp32  (dead after pack) / outpre overlay
  //  [6291456, 6324224)      sqp       (dead after knn)
  //  [6324224, 9469952)      fragH     (dead after knn)
  //  [9469952, 12615680)     fragL     (dead after knn; outpre tail overlaps)
  //  [12615680, 12841472)    nn9 (int) persists
  //  [12841472, ...)         psum | pss | af | bf
  float* buf0 = (float*)d_ws;
  float*  xnT   = buf0;
  float*  sqp   = buf0 + 6291456;
  short8* fragH = (short8*)(buf0 + 6324224);
  short8* fragL = (short8*)(buf0 + 9469952);
  int*    nn9   = (int*)(buf0 + 12615680);
  float*  psum  = buf0 + 12841472;
  float*  pss   = psum + COUT_ * NTILES_;
  float*  af    = pss + COUT_ * NTILES_;
  float*  bfv   = af + COUT_;
  float*  outpre = buf0;   // overlay [0, 9633792)

  const int npad_total = B_ * C_ * (NP_ - N_) + B_ * (NP_ - N_);
  hipLaunchKernelGGL(pad_kernel, dim3((npad_total + 255) / 256), dim3(256), 0, stream,
                     xnT, sqp);
  hipLaunchKernelGGL(norm_kernel, dim3(NPTS_ / 64), dim3(256), 0, stream,
                     x, xnT, sqp);
  hipLaunchKernelGGL(pack_kernel, dim3(8, 6, B_), dim3(256), 0, stream,
                     xnT, fragH, fragL);
  hipLaunchKernelGGL(knn_kernel, dim3((N_ / QPB_) * B_), dim3(256), 0, stream,
                     fragH, fragL, sqp, nn9);
  hipLaunchKernelGGL(fconv_kernel, dim3(7, 8, B_), dim3(256), 0, stream,
                     x, nn9, conv_w, conv_b, outpre, psum, pss);
  hipLaunchKernelGGL(stats_kernel, dim3(COUT_), dim3(64), 0, stream,
                     psum, pss, gamma, beta, af, bfv);
  hipLaunchKernelGGL(act_kernel, dim3((B_ * COUT_ * N_) / (256 * 4)), dim3(256), 0, stream,
                     outpre, af, bfv, out);
}